// Round 1
// baseline (11773.479 us; speedup 1.0000x reference)
//
#include <hip/hip_runtime.h>
#include <math.h>

// Problem constants
constexpr int B_ = 64, T_ = 512, D_ = 258, P_ = 128, H_ = 256, C_ = 100, G_ = 768;

// ---------------------------------------------------------------------------
// proj: h_proj[bt][128] = relu(x[bt][258] @ proj_w[128][258]^T + proj_b)
// One WG stages the transposed weight (258x129 padded) in LDS, then processes
// 64 bt-rows (8 staged at a time, 4 rows per thread for w-reuse in registers).
// ---------------------------------------------------------------------------
__global__ __launch_bounds__(256) void proj_kernel(
    const float* __restrict__ x, const float* __restrict__ pw,
    const float* __restrict__ pb, float* __restrict__ hproj)
{
  __shared__ float wt[258 * 129];   // wt[k*129+p]  (pad 129 -> conflict-free)
  __shared__ float xr[8 * 258];
  __shared__ float pbs[128];
  const int tid = threadIdx.x;

  for (int idx = tid; idx < 128 * 258; idx += 256) {
    int p = idx / 258, k = idx - p * 258;
    wt[k * 129 + p] = pw[idx];                 // coalesced read along k
  }
  if (tid < 128) pbs[tid] = pb[tid];
  __syncthreads();

  const long row0 = (long)blockIdx.x * 64;
  for (int rb = 0; rb < 64; rb += 8) {
    for (int i = tid; i < 8 * 258; i += 256) {
      int rr = i / 258, k = i - rr * 258;
      xr[rr * 258 + k] = x[(row0 + rb + rr) * 258 + k];
    }
    __syncthreads();
    const int half = tid >> 7;                 // 0..1 -> which 4-row quad
    const int p = tid & 127;
    float a0 = pbs[p], a1 = pbs[p], a2 = pbs[p], a3 = pbs[p];
    const float* xb = &xr[half * 4 * 258];
    #pragma unroll 2
    for (int k = 0; k < 258; ++k) {
      float w = wt[k * 129 + p];
      a0 = fmaf(xb[0 * 258 + k], w, a0);
      a1 = fmaf(xb[1 * 258 + k], w, a1);
      a2 = fmaf(xb[2 * 258 + k], w, a2);
      a3 = fmaf(xb[3 * 258 + k], w, a3);
    }
    const long ro = row0 + rb + half * 4;
    hproj[(ro + 0) * 128 + p] = fmaxf(a0, 0.f);
    hproj[(ro + 1) * 128 + p] = fmaxf(a1, 0.f);
    hproj[(ro + 2) * 128 + p] = fmaxf(a2, 0.f);
    hproj[(ro + 3) * 128 + p] = fmaxf(a3, 0.f);
    __syncthreads();
  }
}

// ---------------------------------------------------------------------------
// Persistent GRU direction kernel.
// Grid = 256 WGs x 384 threads. Per direction: 128 WGs = batch-groups x
// hidden-slices. Whh/Wih slices live transposed in LDS for all 512 steps.
// Cross-WG h exchange through global double buffer + per-group atomic barrier
// (RELEASE add / ACQUIRE poll, agent scope). Sync-group members share
// blockIdx%8 so they tend to land on one XCD (perf heuristic only).
// ---------------------------------------------------------------------------
template <int LAYER>
__global__ __launch_bounds__(384) void rec_kernel(
    const float* __restrict__ xin_g,   // L0: hproj [B*T][128]; L1: h1 [B*T][512]
    const float* __restrict__ whh,     // [2][768][256]
    const float* __restrict__ wih,     // [2][768][KX]
    const float* __restrict__ bih, const float* __restrict__ bhh,  // [2][768]
    const int* __restrict__ lens,
    float* __restrict__ out,           // L0: h1 [B*T][512]; L1: hfhb [2][64][256]
    float* __restrict__ stbuf,         // [2][2][64][256] h state double buffer
    int* __restrict__ ctr_base)        // barrier counters, stride 16 ints
{
  constexpr int KX  = (LAYER == 0) ? 128 : 512;
  constexpr int NB  = (LAYER == 0) ? 8 : 16;   // batches per group
  constexpr int SU  = (LAYER == 0) ? 16 : 8;   // hidden units per WG
  constexpr int GR  = 3 * SU;                  // gate rows per WG (48 / 24)
  constexpr int NS  = H_ / SU;                 // slices = barrier width (16/32)
  constexpr int W   = NS;
  constexpr int NGG = GR / 4;                  // g-quads (12 / 6)

  __shared__ float whh_t[H_ * GR];             // [k][g]
  __shared__ float wih_t[KX * GR];             // [k][g]
  __shared__ float xin[NB * KX];
  __shared__ float hcur[NB * H_];
  __shared__ float xp[NB * GR * 8];            // k-split partials
  __shared__ float xgs[NB * GR];
  __shared__ float ghs[NB * GR];
  __shared__ float biasx[GR], biash[GR];

  const int tid = threadIdx.x;
  const int bx = blockIdx.x;
  const int xcd = bx & 7, slot = bx >> 3;
  int sgid, slice;
  if (LAYER == 0) { sgid = xcd + 8 * (slot >> 4); slice = slot & 15; }
  else            { sgid = xcd;                   slice = slot; }
  const int dir   = (LAYER == 0) ? (sgid >> 3) : (sgid >> 2);
  const int group = (LAYER == 0) ? (sgid & 7) : (sgid & 3);
  int* ctr = ctr_base + sgid * 16;

  // ---- init: stage transposed weight slices, biases; zero h state ----
  for (int idx = tid; idx < GR * H_; idx += 384) {
    int g = idx / H_, k = idx - g * H_;
    int gate = g / SU, u = g - gate * SU;
    int rg = gate * H_ + slice * SU + u;
    whh_t[k * GR + g] = whh[((long)dir * G_ + rg) * H_ + k];
  }
  for (int idx = tid; idx < GR * KX; idx += 384) {
    int g = idx / KX, k = idx - g * KX;
    int gate = g / SU, u = g - gate * SU;
    int rg = gate * H_ + slice * SU + u;
    wih_t[k * GR + g] = wih[((long)dir * G_ + rg) * KX + k];
  }
  if (tid < GR) {
    int gate = tid / SU, u = tid - gate * SU;
    int rg = gate * H_ + slice * SU + u;
    biasx[tid] = bih[dir * G_ + rg];
    biash[tid] = bhh[dir * G_ + rg];
  }
  int lenb = 0;
  if (tid < NB * SU) {
    int b = tid / SU, u = tid - b * SU;
    int bg = group * NB + b;
    lenb = max(1, lens[bg]);
    stbuf[((dir * 2 + 0) * B_ + bg) * H_ + slice * SU + u] = 0.f;
  }
  __syncthreads();
  if (tid == 0)
    __hip_atomic_fetch_add(ctr, 1, __ATOMIC_RELEASE, __HIP_MEMORY_SCOPE_AGENT);

  // compute-thread decode: tid = kq*48 + bb*NGG + gq
  const int kq = tid / 48;
  const int rr = tid - kq * 48;
  const int bb = rr / NGG;
  const int gq = rr - bb * NGG;
  const int b0 = bb * 2, b1 = b0 + 1;
  const int g0 = gq * 4;
  const int cb = tid / GR;             // combine mapping: (b,g)
  const int cg = tid - cb * GR;

  for (int ti = 0; ti < T_; ++ti) {
    const int t = dir ? (T_ - 1 - ti) : ti;

    // A: stage static input row(s) for this t
    {
      constexpr int TOT = NB * KX / 4;
      for (int i = tid; i < TOT; i += 384) {
        int bl = i / (KX / 4), k4 = i - bl * (KX / 4);
        long bt = (long)(group * NB + bl) * T_ + t;
        float4 v = *(const float4*)&xin_g[bt * KX + k4 * 4];
        *(float4*)&xin[bl * KX + k4 * 4] = v;
      }
    }
    __syncthreads();

    // B: xg partial dots (2 batches x 4 gate-rows x K/8 per thread)
    {
      constexpr int KS = KX / 8;
      const int k0 = kq * KS;
      float a00 = 0, a01 = 0, a02 = 0, a03 = 0, a10 = 0, a11 = 0, a12 = 0, a13 = 0;
      const float* xb0 = &xin[b0 * KX];
      const float* xb1 = &xin[b1 * KX];
      #pragma unroll 4
      for (int k = k0; k < k0 + KS; ++k) {
        float4 w = *(const float4*)&wih_t[k * GR + g0];
        float h0 = xb0[k], h1v = xb1[k];
        a00 = fmaf(h0, w.x, a00); a01 = fmaf(h0, w.y, a01);
        a02 = fmaf(h0, w.z, a02); a03 = fmaf(h0, w.w, a03);
        a10 = fmaf(h1v, w.x, a10); a11 = fmaf(h1v, w.y, a11);
        a12 = fmaf(h1v, w.z, a12); a13 = fmaf(h1v, w.w, a13);
      }
      xp[(b0 * GR + g0 + 0) * 8 + kq] = a00;
      xp[(b0 * GR + g0 + 1) * 8 + kq] = a01;
      xp[(b0 * GR + g0 + 2) * 8 + kq] = a02;
      xp[(b0 * GR + g0 + 3) * 8 + kq] = a03;
      xp[(b1 * GR + g0 + 0) * 8 + kq] = a10;
      xp[(b1 * GR + g0 + 1) * 8 + kq] = a11;
      xp[(b1 * GR + g0 + 2) * 8 + kq] = a12;
      xp[(b1 * GR + g0 + 3) * 8 + kq] = a13;
    }
    __syncthreads();
    {  // B combine -> xgs
      const float4* p4 = (const float4*)&xp[(cb * GR + cg) * 8];
      float4 u0 = p4[0], u1 = p4[1];
      xgs[tid] = u0.x + u0.y + u0.z + u0.w + u1.x + u1.y + u1.z + u1.w + biasx[cg];
    }

    // C: wait until every slice of this group published h for step ti
    if (tid == 0) {
      const int tgt = (ti + 1) * W;
      while (__hip_atomic_load(ctr, __ATOMIC_RELAXED, __HIP_MEMORY_SCOPE_AGENT) < tgt) {}
      (void)__hip_atomic_load(ctr, __ATOMIC_ACQUIRE, __HIP_MEMORY_SCOPE_AGENT);
    }
    __syncthreads();

    // D: stage h (full 256 per batch) from global double buffer
    {
      constexpr int TOT = NB * H_ / 4;
      const int buf = ti & 1;
      for (int i = tid; i < TOT; i += 384) {
        int bl = i / (H_ / 4), k4 = i - bl * (H_ / 4);
        float4 v = *(const float4*)
            &stbuf[(((dir * 2 + buf) * B_) + group * NB + bl) * H_ + k4 * 4];
        *(float4*)&hcur[bl * H_ + k4 * 4] = v;
      }
    }
    __syncthreads();

    // E: recurrent partial dots
    {
      constexpr int KS = H_ / 8;  // 32
      const int k0 = kq * KS;
      float a00 = 0, a01 = 0, a02 = 0, a03 = 0, a10 = 0, a11 = 0, a12 = 0, a13 = 0;
      const float* hb0 = &hcur[b0 * H_];
      const float* hb1 = &hcur[b1 * H_];
      #pragma unroll 4
      for (int k = k0; k < k0 + KS; ++k) {
        float4 w = *(const float4*)&whh_t[k * GR + g0];
        float h0 = hb0[k], h1v = hb1[k];
        a00 = fmaf(h0, w.x, a00); a01 = fmaf(h0, w.y, a01);
        a02 = fmaf(h0, w.z, a02); a03 = fmaf(h0, w.w, a03);
        a10 = fmaf(h1v, w.x, a10); a11 = fmaf(h1v, w.y, a11);
        a12 = fmaf(h1v, w.z, a12); a13 = fmaf(h1v, w.w, a13);
      }
      xp[(b0 * GR + g0 + 0) * 8 + kq] = a00;
      xp[(b0 * GR + g0 + 1) * 8 + kq] = a01;
      xp[(b0 * GR + g0 + 2) * 8 + kq] = a02;
      xp[(b0 * GR + g0 + 3) * 8 + kq] = a03;
      xp[(b1 * GR + g0 + 0) * 8 + kq] = a10;
      xp[(b1 * GR + g0 + 1) * 8 + kq] = a11;
      xp[(b1 * GR + g0 + 2) * 8 + kq] = a12;
      xp[(b1 * GR + g0 + 3) * 8 + kq] = a13;
    }
    __syncthreads();
    {  // E combine -> ghs
      const float4* p4 = (const float4*)&xp[(cb * GR + cg) * 8];
      float4 u0 = p4[0], u1 = p4[1];
      ghs[tid] = u0.x + u0.y + u0.z + u0.w + u1.x + u1.y + u1.z + u1.w + biash[cg];
    }
    __syncthreads();

    // F: gate math, mask, publish h slice
    if (tid < NB * SU) {
      const int b = tid / SU, u = tid - b * SU;
      const int jg = slice * SU + u;
      const int bg = group * NB + b;
      float xr_ = xgs[b * GR + u], xz_ = xgs[b * GR + SU + u], xn_ = xgs[b * GR + 2 * SU + u];
      float hr_ = ghs[b * GR + u], hz_ = ghs[b * GR + SU + u], hn_ = ghs[b * GR + 2 * SU + u];
      float r_ = 1.f / (1.f + expf(-(xr_ + hr_)));
      float z_ = 1.f / (1.f + expf(-(xz_ + hz_)));
      float n_ = tanhf(xn_ + r_ * hn_);
      float hold = hcur[b * H_ + jg];
      float hnew = (1.f - z_) * n_ + z_ * hold;
      float hv = (t < lenb) ? hnew : hold;
      stbuf[((dir * 2 + ((ti + 1) & 1)) * B_ + bg) * H_ + jg] = hv;
      if (LAYER == 0)
        out[((long)bg * T_ + t) * (2 * H_) + dir * H_ + jg] = hv;
      else if (ti == T_ - 1)
        out[(dir * B_ + bg) * H_ + jg] = hv;
    }

    // G: arrive
    __syncthreads();
    if (tid == 0)
      __hip_atomic_fetch_add(ctr, 1, __ATOMIC_RELEASE, __HIP_MEMORY_SCOPE_AGENT);
  }
}

// ---------------------------------------------------------------------------
// Final: LayerNorm(concat(hf,hb)) @ fc_w^T + fc_b   -> out[64][100]
// ---------------------------------------------------------------------------
__global__ __launch_bounds__(128) void final_kernel(
    const float* __restrict__ hfhb, const float* __restrict__ lng,
    const float* __restrict__ lnb, const float* __restrict__ fcw,
    const float* __restrict__ fcb, float* __restrict__ out)
{
  const int b = blockIdx.x, tid = threadIdx.x;
  __shared__ float y[512];
  __shared__ float wsum[2], wsum2[2];
  float s = 0, s2 = 0;
  for (int i = tid; i < 512; i += 128) {
    float v = (i < 256) ? hfhb[b * 256 + i] : hfhb[(64 + b) * 256 + (i - 256)];
    y[i] = v; s += v; s2 += v * v;
  }
  for (int off = 32; off; off >>= 1) { s += __shfl_down(s, off); s2 += __shfl_down(s2, off); }
  const int wv = tid >> 6;
  if ((tid & 63) == 0) { wsum[wv] = s; wsum2[wv] = s2; }
  __syncthreads();
  const float S = wsum[0] + wsum[1], S2 = wsum2[0] + wsum2[1];
  const float mu = S / 512.f;
  const float var = S2 / 512.f - mu * mu;
  const float rs = rsqrtf(var + 1e-5f);
  for (int i = tid; i < 512; i += 128) y[i] = (y[i] - mu) * rs * lng[i] + lnb[i];
  __syncthreads();
  for (int c = tid; c < 100; c += 128) {
    float acc = fcb[c];
    const float* wr = &fcw[c * 512];
    #pragma unroll 4
    for (int k = 0; k < 512; ++k) acc = fmaf(y[k], wr[k], acc);
    out[b * 100 + c] = acc;
  }
}

// ---------------------------------------------------------------------------
extern "C" void kernel_launch(void* const* d_in, const int* in_sizes, int n_in,
                              void* d_out, int out_size, void* d_ws, size_t ws_size,
                              hipStream_t stream)
{
  (void)in_sizes; (void)n_in; (void)out_size; (void)ws_size;
  const float* x    = (const float*)d_in[0];
  const float* pw   = (const float*)d_in[1];
  const float* pb   = (const float*)d_in[2];
  const float* wih0 = (const float*)d_in[3];
  const float* whh0 = (const float*)d_in[4];
  const float* bih0 = (const float*)d_in[5];
  const float* bhh0 = (const float*)d_in[6];
  const float* wih1 = (const float*)d_in[7];
  const float* whh1 = (const float*)d_in[8];
  const float* bih1 = (const float*)d_in[9];
  const float* bhh1 = (const float*)d_in[10];
  const float* lng  = (const float*)d_in[11];
  const float* lnb  = (const float*)d_in[12];
  const float* fcw  = (const float*)d_in[13];
  const float* fcb  = (const float*)d_in[14];
  const int*   lens = (const int*)d_in[15];
  float* out = (float*)d_out;

  char* ws = (char*)d_ws;
  int*   ctr   = (int*)ws;                                   //   4 KB counters
  float* hproj = (float*)(ws + 4096);                        //  16 MB
  float* h1    = (float*)(ws + 4096 + 16777216);             //  64 MB
  float* stb   = (float*)(ws + 4096 + 16777216 + 67108864);  // 512 KB
  float* hfhb  = (float*)(ws + 4096 + 16777216 + 67108864 + 524288);  // 128 KB

  hipMemsetAsync(ctr, 0, 4096, stream);
  proj_kernel<<<dim3(512), dim3(256), 0, stream>>>(x, pw, pb, hproj);
  rec_kernel<0><<<dim3(256), dim3(384), 0, stream>>>(
      hproj, whh0, wih0, bih0, bhh0, lens, h1, stb, ctr);
  rec_kernel<1><<<dim3(256), dim3(384), 0, stream>>>(
      h1, whh1, wih1, bih1, bhh1, lens, hfhb, stb, ctr + 256);
  final_kernel<<<dim3(64), dim3(128), 0, stream>>>(hfhb, lng, lnb, fcw, fcb, out);
}

// Round 2
// 9956.523 us; speedup vs baseline: 1.1825x; 1.1825x over previous
//
#include <hip/hip_runtime.h>
#include <math.h>

constexpr int B_ = 64, T_ = 512, H_ = 256;

// ---------------------------------------------------------------------------
// Generic tiled fp32 GEMM: C[m][n] = act( sum_k A[arow(m)][k]*W[n][k] + bias[n] )
// BM=BN=128, BK=32, 256 threads, 8x8 micro-tile. grid = mtiles*ntiles*dirs.
// CHUNKMAP: A row = (m>>7)*512 + tbase + (m&127)  (b-major chunks of 128 t)
// dir selects W/bias offset (+dir*768*K / +dir*768) and C0/C1 output.
// ---------------------------------------------------------------------------
template <bool CHUNKMAP, bool RELU>
__global__ __launch_bounds__(256) void gemm_kernel(
    const float* __restrict__ A, const float* __restrict__ Wt,
    const float* __restrict__ bias, float* __restrict__ C0,
    float* __restrict__ C1, int K, int N, int mtiles, int ntiles,
    int tb0, int tb1)
{
  __shared__ float As[32][132];
  __shared__ float Bs[32][132];
  int bxx = blockIdx.x;
  const int mt = bxx % mtiles; bxx /= mtiles;
  const int nt = bxx % ntiles; const int dir = bxx / ntiles;
  const float* Wd = Wt + (long)dir * 768 * K;
  const float* bd = bias + dir * 768;
  float* Cd = dir ? C1 : C0;
  const int tbase = dir ? tb1 : tb0;
  const int tid = threadIdx.x;
  const int tx = tid & 15, ty = tid >> 4;

  float acc[8][8];
  #pragma unroll
  for (int i = 0; i < 8; ++i)
    #pragma unroll
    for (int j = 0; j < 8; ++j) acc[i][j] = 0.f;

  const int KB = (K + 31) >> 5;
  for (int kb = 0; kb < KB; ++kb) {
    __syncthreads();
    #pragma unroll
    for (int e = 0; e < 16; ++e) {
      const int i = e * 256 + tid;
      const int r = i >> 5, kk = i & 31;
      const int kg = kb * 32 + kk;
      const int m = mt * 128 + r;
      long ar;
      if (CHUNKMAP) ar = (long)(m >> 7) * 512 + tbase + (m & 127);
      else          ar = m;
      As[kk][r] = (kg < K) ? A[ar * K + kg] : 0.f;
      Bs[kk][r] = (kg < K) ? Wd[(long)(nt * 128 + r) * K + kg] : 0.f;
    }
    __syncthreads();
    #pragma unroll 4
    for (int kk = 0; kk < 32; ++kk) {
      float a[8], b[8];
      #pragma unroll
      for (int i = 0; i < 8; ++i) a[i] = As[kk][i * 16 + ty];
      #pragma unroll
      for (int j = 0; j < 8; ++j) b[j] = Bs[kk][j * 16 + tx];
      #pragma unroll
      for (int i = 0; i < 8; ++i)
        #pragma unroll
        for (int j = 0; j < 8; ++j) acc[i][j] = fmaf(a[i], b[j], acc[i][j]);
    }
  }
  #pragma unroll
  for (int j = 0; j < 8; ++j) {
    const int n = nt * 128 + j * 16 + tx;
    const float bv = bd[n];
    #pragma unroll
    for (int i = 0; i < 8; ++i) {
      const int m = mt * 128 + i * 16 + ty;
      float v = acc[i][j] + bv;
      if (RELU) v = fmaxf(v, 0.f);
      Cd[(long)m * N + n] = v;
    }
  }
}

// ---------------------------------------------------------------------------
// Persistent GRU recurrence, xg precomputed. 256 WGs x 768 threads.
// WG = (sgid = dir*16+group [4 batches], slice [32 hidden units]).
// Whh slice rows live in REGISTERS (2 rows x 64 k per thread = 128 VGPR).
// Thread = (kh = tid&3 [64-k slice], idx = tid>>2 -> b = idx/48, gp = idx%48).
// Reduction over kh via 2 shfl_xor. 8-wide same-XCD barrier per step.
// Processes 128 steps per launch (chunk), state persists in stbuf.
// ---------------------------------------------------------------------------
template <int LAYER>
__global__ __launch_bounds__(768) void rec_kernel(
    const float* __restrict__ xgf, const float* __restrict__ xgb,
    const float* __restrict__ whh, const float* __restrict__ bhh,
    const int* __restrict__ lens, float* __restrict__ out,
    float* __restrict__ stbuf, int* __restrict__ ctr_base, int sbase)
{
  // hcur[b][kh][i]: b-stride 292 words (==4 mod 32), kh-stride 72 (==8 mod 32)
  __shared__ float hcur[4 * 292];
  __shared__ float ghs[4 * 96];

  const int tid = threadIdx.x;
  const int bx = blockIdx.x;
  const int sgid = bx & 31, slice = bx >> 5;
  const int dir = sgid >> 4, group = sgid & 15;
  int* ctr = ctr_base + sgid * 16;

  // E decode
  const int kh = tid & 3;
  const int idx = tid >> 2;        // 0..191
  const int eb = idx / 48;         // batch 0..3
  const int gp = idx - eb * 48;    // gate-pair 0..47

  // Whh rows 2gp, 2gp+1 (local g -> rg = (g>>5)*256 + slice*32 + (g&31)),
  // k in [kh*64, kh*64+64): 32 float4 = 128 VGPRs, loaded once per chunk.
  float4 w0[16], w1[16];
  {
    const int g0l = gp * 2, g1l = g0l + 1;
    const int rg0 = ((g0l >> 5) << 8) + slice * 32 + (g0l & 31);
    const int rg1 = ((g1l >> 5) << 8) + slice * 32 + (g1l & 31);
    const float* wr0 = whh + ((long)dir * 768 + rg0) * 256 + kh * 64;
    const float* wr1 = whh + ((long)dir * 768 + rg1) * 256 + kh * 64;
    #pragma unroll
    for (int iq = 0; iq < 16; ++iq) w0[iq] = ((const float4*)wr0)[iq];
    #pragma unroll
    for (int iq = 0; iq < 16; ++iq) w1[iq] = ((const float4*)wr1)[iq];
  }

  // gate-thread setup (tid < 128): (bgate, u)
  const int bgate = tid >> 5, u = tid & 31;
  const int jg = slice * 32 + u;
  const int bg_g = group * 4 + bgate;
  float bhr = 0.f, bhz = 0.f, bhn = 0.f;
  int lenb = 1;
  if (tid < 128) {
    bhr = bhh[dir * 768 + jg];
    bhz = bhh[dir * 768 + 256 + jg];
    bhn = bhh[dir * 768 + 512 + jg];
    lenb = max(1, lens[bg_g]);
  }
  const float* xg_my = (dir == 0) ? xgf : xgb;

  if (sbase == 0) {  // chunk 0: zero state, initial arrive
    if (tid < 128)
      stbuf[((dir * 2 + 0) * B_ + bg_g) * H_ + jg] = 0.f;
    __syncthreads();
    if (tid == 0)
      __hip_atomic_fetch_add(ctr, 1, __ATOMIC_RELEASE, __HIP_MEMORY_SCOPE_AGENT);
  }

  for (int ti = 0; ti < 128; ++ti) {
    const int s = sbase + ti;
    const int t = dir ? (T_ - 1 - s) : s;
    const int tt = dir ? (127 - ti) : ti;

    if (tid == 0) {
      const int tgt = 8 * (s + 1);
      while (__hip_atomic_load(ctr, __ATOMIC_ACQUIRE, __HIP_MEMORY_SCOPE_AGENT) < tgt) {}
    }
    __syncthreads();

    // xg prefetch (gate threads) + h staging (first 256 threads)
    float xrv = 0.f, xzv = 0.f, xnv = 0.f;
    if (tid < 128) {
      const float* xrow = xg_my + ((long)bg_g * 128 + tt) * 768;
      xrv = xrow[jg];
      xzv = xrow[256 + jg];
      xnv = xrow[512 + jg];
    }
    if (tid < 256) {
      const int bl = tid >> 6, k4 = tid & 63;     // k = k4*4
      const int rb = s & 1;
      float4 v = *(const float4*)&stbuf[(((dir * 2 + rb) * B_) + group * 4 + bl) * H_ + k4 * 4];
      *(float4*)&hcur[bl * 292 + (k4 >> 4) * 72 + (k4 & 15) * 4] = v;
    }
    __syncthreads();

    // E: 2 gate rows x 64 k per thread, all weights in registers
    {
      float4 A0 = {0.f, 0.f, 0.f, 0.f}, A1 = {0.f, 0.f, 0.f, 0.f};
      const float* hb = &hcur[eb * 292 + kh * 72];
      #pragma unroll
      for (int iq = 0; iq < 16; ++iq) {
        float4 h4 = *(const float4*)&hb[iq * 4];
        A0.x = fmaf(w0[iq].x, h4.x, A0.x);
        A0.y = fmaf(w0[iq].y, h4.y, A0.y);
        A0.z = fmaf(w0[iq].z, h4.z, A0.z);
        A0.w = fmaf(w0[iq].w, h4.w, A0.w);
        A1.x = fmaf(w1[iq].x, h4.x, A1.x);
        A1.y = fmaf(w1[iq].y, h4.y, A1.y);
        A1.z = fmaf(w1[iq].z, h4.z, A1.z);
        A1.w = fmaf(w1[iq].w, h4.w, A1.w);
      }
      float s0 = (A0.x + A0.y) + (A0.z + A0.w);
      float s1 = (A1.x + A1.y) + (A1.z + A1.w);
      s0 += __shfl_xor(s0, 1); s0 += __shfl_xor(s0, 2);
      s1 += __shfl_xor(s1, 1); s1 += __shfl_xor(s1, 2);
      if (kh == 0)      ghs[eb * 96 + gp * 2]     = s0;
      else if (kh == 1) ghs[eb * 96 + gp * 2 + 1] = s1;
    }
    __syncthreads();

    // gates + publish
    if (tid < 128) {
      const float gr_ = ghs[bgate * 96 + u]      + bhr;
      const float gz_ = ghs[bgate * 96 + 32 + u] + bhz;
      const float gn_ = ghs[bgate * 96 + 64 + u] + bhn;
      const float r_ = 1.f / (1.f + expf(-(xrv + gr_)));
      const float z_ = 1.f / (1.f + expf(-(xzv + gz_)));
      const float n_ = tanhf(xnv + r_ * gn_);
      const float hold = hcur[bgate * 292 + (jg >> 6) * 72 + (jg & 63)];
      const float hv = (t < lenb) ? ((1.f - z_) * n_ + z_ * hold) : hold;
      stbuf[((dir * 2 + ((s + 1) & 1)) * B_ + bg_g) * H_ + jg] = hv;
      if (LAYER == 0)
        out[((long)bg_g * T_ + t) * 512 + dir * 256 + jg] = hv;
      else if (s == T_ - 1)
        out[(dir * B_ + bg_g) * H_ + jg] = hv;
    }
    __syncthreads();
    if (tid == 0)
      __hip_atomic_fetch_add(ctr, 1, __ATOMIC_RELEASE, __HIP_MEMORY_SCOPE_AGENT);
  }
}

// ---------------------------------------------------------------------------
// Final: LayerNorm(concat(hf,hb)) @ fc_w^T + fc_b -> out[64][100]
// ---------------------------------------------------------------------------
__global__ __launch_bounds__(128) void final_kernel(
    const float* __restrict__ hfhb, const float* __restrict__ lng,
    const float* __restrict__ lnb, const float* __restrict__ fcw,
    const float* __restrict__ fcb, float* __restrict__ out)
{
  const int b = blockIdx.x, tid = threadIdx.x;
  __shared__ float y[512];
  __shared__ float wsum[2], wsum2[2];
  float s = 0.f, s2 = 0.f;
  for (int i = tid; i < 512; i += 128) {
    float v = (i < 256) ? hfhb[b * 256 + i] : hfhb[(64 + b) * 256 + (i - 256)];
    y[i] = v; s += v; s2 += v * v;
  }
  for (int off = 32; off; off >>= 1) { s += __shfl_down(s, off); s2 += __shfl_down(s2, off); }
  const int wv = tid >> 6;
  if ((tid & 63) == 0) { wsum[wv] = s; wsum2[wv] = s2; }
  __syncthreads();
  const float S = wsum[0] + wsum[1], S2 = wsum2[0] + wsum2[1];
  const float mu = S / 512.f;
  const float var = S2 / 512.f - mu * mu;
  const float rs = rsqrtf(var + 1e-5f);
  for (int i = tid; i < 512; i += 128) y[i] = (y[i] - mu) * rs * lng[i] + lnb[i];
  __syncthreads();
  for (int c = tid; c < 100; c += 128) {
    float acc = fcb[c];
    const float* wr = &fcw[c * 512];
    #pragma unroll 4
    for (int k = 0; k < 512; ++k) acc = fmaf(y[k], wr[k], acc);
    out[b * 100 + c] = acc;
  }
}

// ---------------------------------------------------------------------------
extern "C" void kernel_launch(void* const* d_in, const int* in_sizes, int n_in,
                              void* d_out, int out_size, void* d_ws, size_t ws_size,
                              hipStream_t stream)
{
  (void)in_sizes; (void)n_in; (void)out_size; (void)ws_size;
  const float* x    = (const float*)d_in[0];
  const float* pw   = (const float*)d_in[1];
  const float* pb   = (const float*)d_in[2];
  const float* wih0 = (const float*)d_in[3];
  const float* whh0 = (const float*)d_in[4];
  const float* bih0 = (const float*)d_in[5];
  const float* bhh0 = (const float*)d_in[6];
  const float* wih1 = (const float*)d_in[7];
  const float* whh1 = (const float*)d_in[8];
  const float* bih1 = (const float*)d_in[9];
  const float* bhh1 = (const float*)d_in[10];
  const float* lng  = (const float*)d_in[11];
  const float* lnb  = (const float*)d_in[12];
  const float* fcw  = (const float*)d_in[13];
  const float* fcb  = (const float*)d_in[14];
  const int*   lens = (const int*)d_in[15];
  float* out = (float*)d_out;

  char* ws = (char*)d_ws;
  int*   ctr   = (int*)ws;                             // 4 KB (L0: +0, L1: +512 ints)
  float* hproj = (float*)(ws + 4096);                  // 32768x128   (16.78 MB)
  float* h1    = (float*)(ws + 16781312);              // 32768x512   (67.11 MB)
  float* xgf   = (float*)(ws + 83890176);              // 64x128x768  (25.17 MB)
  float* xgb   = (float*)(ws + 109056000);             // 64x128x768  (25.17 MB)
  float* stbuf = (float*)(ws + 134221824);             // 2x2x64x256  (0.52 MB)
  float* hfhb  = (float*)(ws + 134746112);             // 2x64x256    (0.13 MB)

  hipMemsetAsync(ctr, 0, 4096, stream);

  // proj: relu(x @ pw^T + pb) -> hproj  (M=32768, N=128, K=258)
  gemm_kernel<false, true><<<dim3(256), dim3(256), 0, stream>>>(
      x, pw, pb, hproj, hproj, 258, 128, 256, 1, 0, 0);

  // Layer 0: per phase p, xg for fwd chunk p and bwd chunk 3-p, then 128 rec steps
  for (int p = 0; p < 4; ++p) {
    gemm_kernel<true, false><<<dim3(768), dim3(256), 0, stream>>>(
        hproj, wih0, bih0, xgf, xgb, 128, 768, 64, 6, p * 128, (3 - p) * 128);
    rec_kernel<0><<<dim3(256), dim3(768), 0, stream>>>(
        xgf, xgb, whh0, bhh0, lens, h1, stbuf, ctr, p * 128);
  }
  // Layer 1
  for (int p = 0; p < 4; ++p) {
    gemm_kernel<true, false><<<dim3(768), dim3(256), 0, stream>>>(
        h1, wih1, bih1, xgf, xgb, 512, 768, 64, 6, p * 128, (3 - p) * 128);
    rec_kernel<1><<<dim3(256), dim3(768), 0, stream>>>(
        xgf, xgb, whh1, bhh1, lens, hfhb, stbuf, ctr + 512, p * 128);
  }

  final_kernel<<<dim3(64), dim3(128), 0, stream>>>(hfhb, lng, lnb, fcw, fcb, out);
}

// Round 3
// 8388.634 us; speedup vs baseline: 1.4035x; 1.1869x over previous
//
#include <hip/hip_runtime.h>
#include <math.h>

constexpr int B_ = 64, T_ = 512, H_ = 256;

// ---------------------------------------------------------------------------
// Generic tiled fp32 GEMM: C[m][n] = act( sum_k A[arow(m)][k]*W[n][k] + bias[n] )
// BM=BN=128, BK=32, 256 threads, 8x8 micro-tile. grid = mtiles*ntiles*dirs.
// CHUNKMAP: A row = (m>>7)*512 + tbase + (m&127)  (b-major chunks of 128 t)
// dir selects W/bias offset (+dir*768*K / +dir*768) and C0/C1 output.
// ---------------------------------------------------------------------------
template <bool CHUNKMAP, bool RELU>
__global__ __launch_bounds__(256) void gemm_kernel(
    const float* __restrict__ A, const float* __restrict__ Wt,
    const float* __restrict__ bias, float* __restrict__ C0,
    float* __restrict__ C1, int K, int N, int mtiles, int ntiles,
    int tb0, int tb1)
{
  __shared__ float As[32][132];
  __shared__ float Bs[32][132];
  int bxx = blockIdx.x;
  const int mt = bxx % mtiles; bxx /= mtiles;
  const int nt = bxx % ntiles; const int dir = bxx / ntiles;
  const float* Wd = Wt + (long)dir * 768 * K;
  const float* bd = bias + dir * 768;
  float* Cd = dir ? C1 : C0;
  const int tbase = dir ? tb1 : tb0;
  const int tid = threadIdx.x;
  const int tx = tid & 15, ty = tid >> 4;

  float acc[8][8];
  #pragma unroll
  for (int i = 0; i < 8; ++i)
    #pragma unroll
    for (int j = 0; j < 8; ++j) acc[i][j] = 0.f;

  const int KB = (K + 31) >> 5;
  for (int kb = 0; kb < KB; ++kb) {
    __syncthreads();
    #pragma unroll
    for (int e = 0; e < 16; ++e) {
      const int i = e * 256 + tid;
      const int r = i >> 5, kk = i & 31;
      const int kg = kb * 32 + kk;
      const int m = mt * 128 + r;
      long ar;
      if (CHUNKMAP) ar = (long)(m >> 7) * 512 + tbase + (m & 127);
      else          ar = m;
      As[kk][r] = (kg < K) ? A[ar * K + kg] : 0.f;
      Bs[kk][r] = (kg < K) ? Wd[(long)(nt * 128 + r) * K + kg] : 0.f;
    }
    __syncthreads();
    #pragma unroll 4
    for (int kk = 0; kk < 32; ++kk) {
      float a[8], b[8];
      #pragma unroll
      for (int i = 0; i < 8; ++i) a[i] = As[kk][i * 16 + ty];
      #pragma unroll
      for (int j = 0; j < 8; ++j) b[j] = Bs[kk][j * 16 + tx];
      #pragma unroll
      for (int i = 0; i < 8; ++i)
        #pragma unroll
        for (int j = 0; j < 8; ++j) acc[i][j] = fmaf(a[i], b[j], acc[i][j]);
    }
  }
  #pragma unroll
  for (int j = 0; j < 8; ++j) {
    const int n = nt * 128 + j * 16 + tx;
    const float bv = bd[n];
    #pragma unroll
    for (int i = 0; i < 8; ++i) {
      const int m = mt * 128 + i * 16 + ty;
      float v = acc[i][j] + bv;
      if (RELU) v = fmaxf(v, 0.f);
      Cd[(long)m * N + n] = v;
    }
  }
}

// ---------------------------------------------------------------------------
// Persistent GRU recurrence, xg precomputed. 256 WGs x 768 threads.
// WG = (sgid = dir*16+group [4 batches], slice [32 hidden units]).
// Whh slice rows live in REGISTERS (2 rows x 64 k per thread = 128 VGPR).
// __launch_bounds__(768, 3): 1 block/CU = 3 waves/EU -> VGPR budget ~512,
// so the compiler can keep the weight arrays resident (r2's 84-VGPR alloc
// targeted 6 waves/EU and re-loaded weights from L2 every step).
// Thread = (kh = tid&3 [64-k slice], idx = tid>>2 -> b = idx/48, gp = idx%48).
// Reduction over kh via 2 shfl_xor. 8-wide same-XCD barrier per step.
// Processes 128 steps per launch (chunk), state persists in stbuf.
// ---------------------------------------------------------------------------
template <int LAYER>
__global__ __launch_bounds__(768, 3) void rec_kernel(
    const float* __restrict__ xgf, const float* __restrict__ xgb,
    const float* __restrict__ whh, const float* __restrict__ bhh,
    const int* __restrict__ lens, float* __restrict__ out,
    float* __restrict__ stbuf, int* __restrict__ ctr_base, int sbase)
{
  // hcur[b][kh][i]: b-stride 292 words (==4 mod 32), kh-stride 72 (==8 mod 32)
  __shared__ float hcur[4 * 292];
  __shared__ float ghs[4 * 96];

  const int tid = threadIdx.x;
  const int bx = blockIdx.x;
  const int sgid = bx & 31, slice = bx >> 5;
  const int dir = sgid >> 4, group = sgid & 15;
  int* ctr = ctr_base + sgid * 16;

  // E decode
  const int kh = tid & 3;
  const int idx = tid >> 2;        // 0..191
  const int eb = idx / 48;         // batch 0..3
  const int gp = idx - eb * 48;    // gate-pair 0..47

  // Whh rows 2gp, 2gp+1 (local g -> rg = (g>>5)*256 + slice*32 + (g&31)),
  // k in [kh*64, kh*64+64): 32 float4 = 128 VGPRs, loaded once per chunk.
  float4 w0[16], w1[16];
  {
    const int g0l = gp * 2, g1l = g0l + 1;
    const int rg0 = ((g0l >> 5) << 8) + slice * 32 + (g0l & 31);
    const int rg1 = ((g1l >> 5) << 8) + slice * 32 + (g1l & 31);
    const float* wr0 = whh + ((long)dir * 768 + rg0) * 256 + kh * 64;
    const float* wr1 = whh + ((long)dir * 768 + rg1) * 256 + kh * 64;
    #pragma unroll
    for (int iq = 0; iq < 16; ++iq) w0[iq] = ((const float4*)wr0)[iq];
    #pragma unroll
    for (int iq = 0; iq < 16; ++iq) w1[iq] = ((const float4*)wr1)[iq];
  }

  // gate-thread setup (tid < 128): (bgate, u)
  const int bgate = tid >> 5, u = tid & 31;
  const int jg = slice * 32 + u;
  const int bg_g = group * 4 + bgate;
  float bhr = 0.f, bhz = 0.f, bhn = 0.f;
  int lenb = 1;
  if (tid < 128) {
    bhr = bhh[dir * 768 + jg];
    bhz = bhh[dir * 768 + 256 + jg];
    bhn = bhh[dir * 768 + 512 + jg];
    lenb = max(1, lens[bg_g]);
  }
  const float* xg_my = (dir == 0) ? xgf : xgb;

  if (sbase == 0) {  // chunk 0: zero state, initial arrive
    if (tid < 128)
      stbuf[((dir * 2 + 0) * B_ + bg_g) * H_ + jg] = 0.f;
    __syncthreads();
    if (tid == 0)
      __hip_atomic_fetch_add(ctr, 1, __ATOMIC_RELEASE, __HIP_MEMORY_SCOPE_AGENT);
  }

  for (int ti = 0; ti < 128; ++ti) {
    const int s = sbase + ti;
    const int t = dir ? (T_ - 1 - s) : s;
    const int tt = dir ? (127 - ti) : ti;

    // xg prefetch (h-independent): issue BEFORE the barrier poll so the
    // ~300cy global-load latency hides under the spin.
    float xrv = 0.f, xzv = 0.f, xnv = 0.f;
    if (tid < 128) {
      const float* xrow = xg_my + ((long)bg_g * 128 + tt) * 768;
      xrv = xrow[jg];
      xzv = xrow[256 + jg];
      xnv = xrow[512 + jg];
    }

    if (tid == 0) {
      const int tgt = 8 * (s + 1);
      while (__hip_atomic_load(ctr, __ATOMIC_RELAXED, __HIP_MEMORY_SCOPE_AGENT) < tgt) {}
      (void)__hip_atomic_load(ctr, __ATOMIC_ACQUIRE, __HIP_MEMORY_SCOPE_AGENT);
    }
    __syncthreads();

    // h staging (first 256 threads)
    if (tid < 256) {
      const int bl = tid >> 6, k4 = tid & 63;     // k = k4*4
      const int rb = s & 1;
      float4 v = *(const float4*)&stbuf[(((dir * 2 + rb) * B_) + group * 4 + bl) * H_ + k4 * 4];
      *(float4*)&hcur[bl * 292 + (k4 >> 4) * 72 + (k4 & 15) * 4] = v;
    }
    __syncthreads();

    // E: 2 gate rows x 64 k per thread, all weights in registers
    {
      float4 A0 = {0.f, 0.f, 0.f, 0.f}, A1 = {0.f, 0.f, 0.f, 0.f};
      const float* hb = &hcur[eb * 292 + kh * 72];
      #pragma unroll
      for (int iq = 0; iq < 16; ++iq) {
        float4 h4 = *(const float4*)&hb[iq * 4];
        A0.x = fmaf(w0[iq].x, h4.x, A0.x);
        A0.y = fmaf(w0[iq].y, h4.y, A0.y);
        A0.z = fmaf(w0[iq].z, h4.z, A0.z);
        A0.w = fmaf(w0[iq].w, h4.w, A0.w);
        A1.x = fmaf(w1[iq].x, h4.x, A1.x);
        A1.y = fmaf(w1[iq].y, h4.y, A1.y);
        A1.z = fmaf(w1[iq].z, h4.z, A1.z);
        A1.w = fmaf(w1[iq].w, h4.w, A1.w);
      }
      float s0 = (A0.x + A0.y) + (A0.z + A0.w);
      float s1 = (A1.x + A1.y) + (A1.z + A1.w);
      s0 += __shfl_xor(s0, 1); s0 += __shfl_xor(s0, 2);
      s1 += __shfl_xor(s1, 1); s1 += __shfl_xor(s1, 2);
      if (kh == 0)      ghs[eb * 96 + gp * 2]     = s0;
      else if (kh == 1) ghs[eb * 96 + gp * 2 + 1] = s1;
    }
    __syncthreads();

    // gates + publish
    if (tid < 128) {
      const float gr_ = ghs[bgate * 96 + u]      + bhr;
      const float gz_ = ghs[bgate * 96 + 32 + u] + bhz;
      const float gn_ = ghs[bgate * 96 + 64 + u] + bhn;
      const float r_ = 1.f / (1.f + expf(-(xrv + gr_)));
      const float z_ = 1.f / (1.f + expf(-(xzv + gz_)));
      const float n_ = tanhf(xnv + r_ * gn_);
      const float hold = hcur[bgate * 292 + (jg >> 6) * 72 + (jg & 63)];
      const float hv = (t < lenb) ? ((1.f - z_) * n_ + z_ * hold) : hold;
      stbuf[((dir * 2 + ((s + 1) & 1)) * B_ + bg_g) * H_ + jg] = hv;
      if (LAYER == 0)
        out[((long)bg_g * T_ + t) * 512 + dir * 256 + jg] = hv;
      else if (s == T_ - 1)
        out[(dir * B_ + bg_g) * H_ + jg] = hv;
    }
    __syncthreads();
    if (tid == 0)
      __hip_atomic_fetch_add(ctr, 1, __ATOMIC_RELEASE, __HIP_MEMORY_SCOPE_AGENT);
  }
}

// ---------------------------------------------------------------------------
// Final: LayerNorm(concat(hf,hb)) @ fc_w^T + fc_b -> out[64][100]
// ---------------------------------------------------------------------------
__global__ __launch_bounds__(128) void final_kernel(
    const float* __restrict__ hfhb, const float* __restrict__ lng,
    const float* __restrict__ lnb, const float* __restrict__ fcw,
    const float* __restrict__ fcb, float* __restrict__ out)
{
  const int b = blockIdx.x, tid = threadIdx.x;
  __shared__ float y[512];
  __shared__ float wsum[2], wsum2[2];
  float s = 0.f, s2 = 0.f;
  for (int i = tid; i < 512; i += 128) {
    float v = (i < 256) ? hfhb[b * 256 + i] : hfhb[(64 + b) * 256 + (i - 256)];
    y[i] = v; s += v; s2 += v * v;
  }
  for (int off = 32; off; off >>= 1) { s += __shfl_down(s, off); s2 += __shfl_down(s2, off); }
  const int wv = tid >> 6;
  if ((tid & 63) == 0) { wsum[wv] = s; wsum2[wv] = s2; }
  __syncthreads();
  const float S = wsum[0] + wsum[1], S2 = wsum2[0] + wsum2[1];
  const float mu = S / 512.f;
  const float var = S2 / 512.f - mu * mu;
  const float rs = rsqrtf(var + 1e-5f);
  for (int i = tid; i < 512; i += 128) y[i] = (y[i] - mu) * rs * lng[i] + lnb[i];
  __syncthreads();
  for (int c = tid; c < 100; c += 128) {
    float acc = fcb[c];
    const float* wr = &fcw[c * 512];
    #pragma unroll 4
    for (int k = 0; k < 512; ++k) acc = fmaf(y[k], wr[k], acc);
    out[b * 100 + c] = acc;
  }
}

// ---------------------------------------------------------------------------
extern "C" void kernel_launch(void* const* d_in, const int* in_sizes, int n_in,
                              void* d_out, int out_size, void* d_ws, size_t ws_size,
                              hipStream_t stream)
{
  (void)in_sizes; (void)n_in; (void)out_size; (void)ws_size;
  const float* x    = (const float*)d_in[0];
  const float* pw   = (const float*)d_in[1];
  const float* pb   = (const float*)d_in[2];
  const float* wih0 = (const float*)d_in[3];
  const float* whh0 = (const float*)d_in[4];
  const float* bih0 = (const float*)d_in[5];
  const float* bhh0 = (const float*)d_in[6];
  const float* wih1 = (const float*)d_in[7];
  const float* whh1 = (const float*)d_in[8];
  const float* bih1 = (const float*)d_in[9];
  const float* bhh1 = (const float*)d_in[10];
  const float* lng  = (const float*)d_in[11];
  const float* lnb  = (const float*)d_in[12];
  const float* fcw  = (const float*)d_in[13];
  const float* fcb  = (const float*)d_in[14];
  const int*   lens = (const int*)d_in[15];
  float* out = (float*)d_out;

  char* ws = (char*)d_ws;
  int*   ctr   = (int*)ws;                             // 4 KB (L0: +0, L1: +512 ints)
  float* hproj = (float*)(ws + 4096);                  // 32768x128   (16.78 MB)
  float* h1    = (float*)(ws + 16781312);              // 32768x512   (67.11 MB)
  float* xgf   = (float*)(ws + 83890176);              // 64x128x768  (25.17 MB)
  float* xgb   = (float*)(ws + 109056000);             // 64x128x768  (25.17 MB)
  float* stbuf = (float*)(ws + 134221824);             // 2x2x64x256  (0.52 MB)
  float* hfhb  = (float*)(ws + 134746112);             // 2x64x256    (0.13 MB)

  hipMemsetAsync(ctr, 0, 4096, stream);

  // proj: relu(x @ pw^T + pb) -> hproj  (M=32768, N=128, K=258)
  gemm_kernel<false, true><<<dim3(256), dim3(256), 0, stream>>>(
      x, pw, pb, hproj, hproj, 258, 128, 256, 1, 0, 0);

  // Layer 0: per phase p, xg for fwd chunk p and bwd chunk 3-p, then 128 rec steps
  for (int p = 0; p < 4; ++p) {
    gemm_kernel<true, false><<<dim3(768), dim3(256), 0, stream>>>(
        hproj, wih0, bih0, xgf, xgb, 128, 768, 64, 6, p * 128, (3 - p) * 128);
    rec_kernel<0><<<dim3(256), dim3(768), 0, stream>>>(
        xgf, xgb, whh0, bhh0, lens, h1, stbuf, ctr, p * 128);
  }
  // Layer 1
  for (int p = 0; p < 4; ++p) {
    gemm_kernel<true, false><<<dim3(768), dim3(256), 0, stream>>>(
        h1, wih1, bih1, xgf, xgb, 512, 768, 64, 6, p * 128, (3 - p) * 128);
    rec_kernel<1><<<dim3(256), dim3(768), 0, stream>>>(
        xgf, xgb, whh1, bhh1, lens, hfhb, stbuf, ctr + 512, p * 128);
  }

  final_kernel<<<dim3(64), dim3(128), 0, stream>>>(hfhb, lng, lnb, fcw, fcb, out);
}

// Round 4
// 8084.362 us; speedup vs baseline: 1.4563x; 1.0376x over previous
//
#include <hip/hip_runtime.h>
#include <math.h>

constexpr int B_ = 64, T_ = 512, H_ = 256;

// ---------------------------------------------------------------------------
// Generic tiled fp32 GEMM: C[m][n] = act( sum_k A[arow(m)][k]*W[n][k] + bias[n] )
// BM=BN=128, BK=32, 256 threads, 8x8 micro-tile. grid = mtiles*ntiles*dirs.
// CHUNKMAP: A row = (m>>7)*512 + tbase + (m&127)  (b-major chunks of 128 t)
// dir selects W/bias offset (+dir*768*K / +dir*768) and C0/C1 output.
// ---------------------------------------------------------------------------
template <bool CHUNKMAP, bool RELU>
__global__ __launch_bounds__(256) void gemm_kernel(
    const float* __restrict__ A, const float* __restrict__ Wt,
    const float* __restrict__ bias, float* __restrict__ C0,
    float* __restrict__ C1, int K, int N, int mtiles, int ntiles,
    int tb0, int tb1)
{
  __shared__ float As[32][132];
  __shared__ float Bs[32][132];
  int bxx = blockIdx.x;
  const int mt = bxx % mtiles; bxx /= mtiles;
  const int nt = bxx % ntiles; const int dir = bxx / ntiles;
  const float* Wd = Wt + (long)dir * 768 * K;
  const float* bd = bias + dir * 768;
  float* Cd = dir ? C1 : C0;
  const int tbase = dir ? tb1 : tb0;
  const int tid = threadIdx.x;
  const int tx = tid & 15, ty = tid >> 4;

  float acc[8][8];
  #pragma unroll
  for (int i = 0; i < 8; ++i)
    #pragma unroll
    for (int j = 0; j < 8; ++j) acc[i][j] = 0.f;

  const int KB = (K + 31) >> 5;
  for (int kb = 0; kb < KB; ++kb) {
    __syncthreads();
    #pragma unroll
    for (int e = 0; e < 16; ++e) {
      const int i = e * 256 + tid;
      const int r = i >> 5, kk = i & 31;
      const int kg = kb * 32 + kk;
      const int m = mt * 128 + r;
      long ar;
      if (CHUNKMAP) ar = (long)(m >> 7) * 512 + tbase + (m & 127);
      else          ar = m;
      As[kk][r] = (kg < K) ? A[ar * K + kg] : 0.f;
      Bs[kk][r] = (kg < K) ? Wd[(long)(nt * 128 + r) * K + kg] : 0.f;
    }
    __syncthreads();
    #pragma unroll 4
    for (int kk = 0; kk < 32; ++kk) {
      float a[8], b[8];
      #pragma unroll
      for (int i = 0; i < 8; ++i) a[i] = As[kk][i * 16 + ty];
      #pragma unroll
      for (int j = 0; j < 8; ++j) b[j] = Bs[kk][j * 16 + tx];
      #pragma unroll
      for (int i = 0; i < 8; ++i)
        #pragma unroll
        for (int j = 0; j < 8; ++j) acc[i][j] = fmaf(a[i], b[j], acc[i][j]);
    }
  }
  #pragma unroll
  for (int j = 0; j < 8; ++j) {
    const int n = nt * 128 + j * 16 + tx;
    const float bv = bd[n];
    #pragma unroll
    for (int i = 0; i < 8; ++i) {
      const int m = mt * 128 + i * 16 + ty;
      float v = acc[i][j] + bv;
      if (RELU) v = fmaxf(v, 0.f);
      Cd[(long)m * N + n] = v;
    }
  }
}

// Pin a float4 in VGPRs: opaque modification -> compiler cannot rematerialize
// the originating load inside the step loop.
#define KEEP4(v) asm volatile("" : "+v"(v.x), "+v"(v.y), "+v"(v.z), "+v"(v.w))

// ---------------------------------------------------------------------------
// Persistent GRU recurrence, xg precomputed. 256 WGs x 768 threads.
// WG = (sgid = dir*32+group [2 batches], slice [64 hidden units]).
// Thread = (r = tid>>2: 192 gate rows) x (kh = tid&3: 64-k slice).
// Each thread: 16 float4 Whh weights PINNED in registers, 2 batch accums.
// Reduction over kh via 2 shfl_xor. 4-wide same-XCD barrier per step
// (group members bx = sgid + 64*slice -> same bx mod 8).
// Processes 128 steps per launch (chunk), state persists in stbuf.
// ---------------------------------------------------------------------------
template <int LAYER>
__global__ __launch_bounds__(768, 3) void rec_kernel(
    const float* __restrict__ xgf, const float* __restrict__ xgb,
    const float* __restrict__ whh, const float* __restrict__ bhh,
    const int* __restrict__ lens, float* __restrict__ out,
    float* __restrict__ stbuf, int* __restrict__ ctr_base, int sbase)
{
  // hcur[b][kh][i]: b-stride 292 (==4 mod 32), kh-stride 72 (==8 mod 32)
  __shared__ float hcur[2 * 292];
  __shared__ float ghs[2 * 192];

  const int tid = threadIdx.x;
  const int bx = blockIdx.x;
  const int sgid = bx & 63, slice = bx >> 6;       // slice: 64 units
  const int dir = sgid >> 5, group = sgid & 31;    // group: 2 batches
  int* ctr = ctr_base + sgid * 16;

  // E decode
  const int kh = tid & 3;
  const int r = tid >> 2;                          // local gate row 0..191
  const int gate = r >> 6, ur = r & 63;
  const int rg = gate * 256 + slice * 64 + ur;     // global gate row

  // Whh[dir][rg][kh*64 .. +64): 16 float4 = 64 VGPRs, pinned.
  float4 w[16];
  {
    const float* wr = whh + ((long)dir * 768 + rg) * 256 + kh * 64;
    #pragma unroll
    for (int iq = 0; iq < 16; ++iq) w[iq] = ((const float4*)wr)[iq];
    #pragma unroll
    for (int iq = 0; iq < 16; ++iq) KEEP4(w[iq]);
  }

  // gate-thread setup (tid < 128): (bgate, u)
  const int bgate = tid >> 6, u = tid & 63;
  const int jg = slice * 64 + u;
  const int bg_g = group * 2 + bgate;
  float bhr = 0.f, bhz = 0.f, bhn = 0.f;
  int lenb = 1;
  if (tid < 128) {
    bhr = bhh[dir * 768 + jg];
    bhz = bhh[dir * 768 + 256 + jg];
    bhn = bhh[dir * 768 + 512 + jg];
    lenb = max(1, lens[bg_g]);
  }
  const float* xg_my = (dir == 0) ? xgf : xgb;

  if (sbase == 0) {  // chunk 0: zero state buf0, initial arrive
    if (tid < 128)
      stbuf[((dir * 2 + 0) * B_ + bg_g) * H_ + jg] = 0.f;
    __syncthreads();
    if (tid == 0)
      __hip_atomic_fetch_add(ctr, 1, __ATOMIC_RELEASE, __HIP_MEMORY_SCOPE_AGENT);
  }

  for (int ti = 0; ti < 128; ++ti) {
    const int s = sbase + ti;
    const int t = dir ? (T_ - 1 - s) : s;
    const int tt = dir ? (127 - ti) : ti;

    // xg prefetch (h-independent): issue BEFORE the barrier poll.
    float xrv = 0.f, xzv = 0.f, xnv = 0.f;
    if (tid < 128) {
      const float* xrow = xg_my + ((long)bg_g * 128 + tt) * 768;
      xrv = xrow[jg];
      xzv = xrow[256 + jg];
      xnv = xrow[512 + jg];
    }

    if (tid == 0) {
      const int tgt = 4 * (s + 1);
      while (__hip_atomic_load(ctr, __ATOMIC_RELAXED, __HIP_MEMORY_SCOPE_AGENT) < tgt) {}
      (void)__hip_atomic_load(ctr, __ATOMIC_ACQUIRE, __HIP_MEMORY_SCOPE_AGENT);
    }
    __syncthreads();

    // h staging: 2 batches x 256 floats (tid < 128, one float4 each)
    if (tid < 128) {
      const int bl = tid >> 6, k4 = tid & 63;
      const int rb = s & 1;
      float4 v = *(const float4*)
          &stbuf[(((dir * 2 + rb) * B_) + group * 2 + bl) * H_ + k4 * 4];
      *(float4*)&hcur[bl * 292 + (k4 >> 4) * 72 + (k4 & 15) * 4] = v;
    }
    __syncthreads();

    // E: 1 gate row x 64 k x 2 batches per thread, weights in registers
    {
      float4 A0 = {0.f, 0.f, 0.f, 0.f}, A1 = {0.f, 0.f, 0.f, 0.f};
      const float* hb0 = &hcur[kh * 72];
      const float* hb1 = &hcur[292 + kh * 72];
      #pragma unroll
      for (int iq = 0; iq < 16; ++iq) {
        float4 h0 = *(const float4*)&hb0[iq * 4];
        float4 h1v = *(const float4*)&hb1[iq * 4];
        A0.x = fmaf(w[iq].x, h0.x, A0.x);
        A0.y = fmaf(w[iq].y, h0.y, A0.y);
        A0.z = fmaf(w[iq].z, h0.z, A0.z);
        A0.w = fmaf(w[iq].w, h0.w, A0.w);
        A1.x = fmaf(w[iq].x, h1v.x, A1.x);
        A1.y = fmaf(w[iq].y, h1v.y, A1.y);
        A1.z = fmaf(w[iq].z, h1v.z, A1.z);
        A1.w = fmaf(w[iq].w, h1v.w, A1.w);
      }
      float s0 = (A0.x + A0.y) + (A0.z + A0.w);
      float s1 = (A1.x + A1.y) + (A1.z + A1.w);
      s0 += __shfl_xor(s0, 1); s0 += __shfl_xor(s0, 2);
      s1 += __shfl_xor(s1, 1); s1 += __shfl_xor(s1, 2);
      if (kh == 0)      ghs[r] = s0;        // batch 0
      else if (kh == 1) ghs[192 + r] = s1;  // batch 1
    }
    __syncthreads();

    // gates + publish
    if (tid < 128) {
      const float gr_ = ghs[bgate * 192 + u]       + bhr;
      const float gz_ = ghs[bgate * 192 + 64 + u]  + bhz;
      const float gn_ = ghs[bgate * 192 + 128 + u] + bhn;
      const float r_ = 1.f / (1.f + expf(-(xrv + gr_)));
      const float z_ = 1.f / (1.f + expf(-(xzv + gz_)));
      const float n_ = tanhf(xnv + r_ * gn_);
      const float hold = hcur[bgate * 292 + (jg >> 6) * 72 + (jg & 63)];
      const float hv = (t < lenb) ? ((1.f - z_) * n_ + z_ * hold) : hold;
      stbuf[((dir * 2 + ((s + 1) & 1)) * B_ + bg_g) * H_ + jg] = hv;
      if (LAYER == 0)
        out[((long)bg_g * T_ + t) * 512 + dir * 256 + jg] = hv;
      else if (s == T_ - 1)
        out[(dir * B_ + bg_g) * H_ + jg] = hv;
    }
    __syncthreads();
    if (tid == 0)
      __hip_atomic_fetch_add(ctr, 1, __ATOMIC_RELEASE, __HIP_MEMORY_SCOPE_AGENT);
  }
}

// ---------------------------------------------------------------------------
// Final: LayerNorm(concat(hf,hb)) @ fc_w^T + fc_b -> out[64][100]
// ---------------------------------------------------------------------------
__global__ __launch_bounds__(128) void final_kernel(
    const float* __restrict__ hfhb, const float* __restrict__ lng,
    const float* __restrict__ lnb, const float* __restrict__ fcw,
    const float* __restrict__ fcb, float* __restrict__ out)
{
  const int b = blockIdx.x, tid = threadIdx.x;
  __shared__ float y[512];
  __shared__ float wsum[2], wsum2[2];
  float s = 0.f, s2 = 0.f;
  for (int i = tid; i < 512; i += 128) {
    float v = (i < 256) ? hfhb[b * 256 + i] : hfhb[(64 + b) * 256 + (i - 256)];
    y[i] = v; s += v; s2 += v * v;
  }
  for (int off = 32; off; off >>= 1) { s += __shfl_down(s, off); s2 += __shfl_down(s2, off); }
  const int wv = tid >> 6;
  if ((tid & 63) == 0) { wsum[wv] = s; wsum2[wv] = s2; }
  __syncthreads();
  const float S = wsum[0] + wsum[1], S2 = wsum2[0] + wsum2[1];
  const float mu = S / 512.f;
  const float var = S2 / 512.f - mu * mu;
  const float rs = rsqrtf(var + 1e-5f);
  for (int i = tid; i < 512; i += 128) y[i] = (y[i] - mu) * rs * lng[i] + lnb[i];
  __syncthreads();
  for (int c = tid; c < 100; c += 128) {
    float acc = fcb[c];
    const float* wr = &fcw[c * 512];
    #pragma unroll 4
    for (int k = 0; k < 512; ++k) acc = fmaf(y[k], wr[k], acc);
    out[b * 100 + c] = acc;
  }
}

// ---------------------------------------------------------------------------
extern "C" void kernel_launch(void* const* d_in, const int* in_sizes, int n_in,
                              void* d_out, int out_size, void* d_ws, size_t ws_size,
                              hipStream_t stream)
{
  (void)in_sizes; (void)n_in; (void)out_size; (void)ws_size;
  const float* x    = (const float*)d_in[0];
  const float* pw   = (const float*)d_in[1];
  const float* pb   = (const float*)d_in[2];
  const float* wih0 = (const float*)d_in[3];
  const float* whh0 = (const float*)d_in[4];
  const float* bih0 = (const float*)d_in[5];
  const float* bhh0 = (const float*)d_in[6];
  const float* wih1 = (const float*)d_in[7];
  const float* whh1 = (const float*)d_in[8];
  const float* bih1 = (const float*)d_in[9];
  const float* bhh1 = (const float*)d_in[10];
  const float* lng  = (const float*)d_in[11];
  const float* lnb  = (const float*)d_in[12];
  const float* fcw  = (const float*)d_in[13];
  const float* fcb  = (const float*)d_in[14];
  const int*   lens = (const int*)d_in[15];
  float* out = (float*)d_out;

  char* ws = (char*)d_ws;
  int*   ctr   = (int*)ws;                       // 16 KB: L0 at +0, L1 at +1024 ints
  float* hproj = (float*)(ws + 16384);           // 32768x128   (16.78 MB)
  float* h1    = (float*)(ws + 16793600);        // 32768x512   (67.11 MB)
  float* xgf   = (float*)(ws + 83902464);        // 64x128x768  (25.17 MB)
  float* xgb   = (float*)(ws + 109068288);       // 64x128x768  (25.17 MB)
  float* stbuf = (float*)(ws + 134234112);       // 2x2x64x256  (0.52 MB)
  float* hfhb  = (float*)(ws + 134758400);       // 2x64x256    (0.13 MB)

  hipMemsetAsync(ctr, 0, 16384, stream);

  // proj: relu(x @ pw^T + pb) -> hproj  (M=32768, N=128, K=258)
  gemm_kernel<false, true><<<dim3(256), dim3(256), 0, stream>>>(
      x, pw, pb, hproj, hproj, 258, 128, 256, 1, 0, 0);

  // Layer 0: per phase p, xg for fwd chunk p and bwd chunk 3-p, then 128 rec steps
  for (int p = 0; p < 4; ++p) {
    gemm_kernel<true, false><<<dim3(768), dim3(256), 0, stream>>>(
        hproj, wih0, bih0, xgf, xgb, 128, 768, 64, 6, p * 128, (3 - p) * 128);
    rec_kernel<0><<<dim3(256), dim3(768), 0, stream>>>(
        xgf, xgb, whh0, bhh0, lens, h1, stbuf, ctr, p * 128);
  }
  // Layer 1
  for (int p = 0; p < 4; ++p) {
    gemm_kernel<true, false><<<dim3(768), dim3(256), 0, stream>>>(
        h1, wih1, bih1, xgf, xgb, 512, 768, 64, 6, p * 128, (3 - p) * 128);
    rec_kernel<1><<<dim3(256), dim3(768), 0, stream>>>(
        xgf, xgb, whh1, bhh1, lens, hfhb, stbuf, ctr + 1024, p * 128);
  }

  final_kernel<<<dim3(64), dim3(128), 0, stream>>>(hfhb, lng, lnb, fcw, fcb, out);
}

// Round 6
// 7744.503 us; speedup vs baseline: 1.5202x; 1.0439x over previous
//
#include <hip/hip_runtime.h>
#include <math.h>

constexpr int B_ = 64, T_ = 512, H_ = 256;

// ---------------------------------------------------------------------------
// Generic tiled fp32 GEMM: C[m][n] = act( sum_k A[arow(m)][k]*W[n][k] + bias[n] )
// BM=BN=128, BK=32, 256 threads, 8x8 micro-tile. grid = mtiles*ntiles*dirs.
// CHUNKMAP: A row = (m>>7)*512 + tbase + (m&127)  (b-major chunks of 128 t)
// ---------------------------------------------------------------------------
template <bool CHUNKMAP, bool RELU>
__global__ __launch_bounds__(256) void gemm_kernel(
    const float* __restrict__ A, const float* __restrict__ Wt,
    const float* __restrict__ bias, float* __restrict__ C0,
    float* __restrict__ C1, int K, int N, int mtiles, int ntiles,
    int tb0, int tb1)
{
  __shared__ float As[32][132];
  __shared__ float Bs[32][132];
  int bxx = blockIdx.x;
  const int mt = bxx % mtiles; bxx /= mtiles;
  const int nt = bxx % ntiles; const int dir = bxx / ntiles;
  const float* Wd = Wt + (long)dir * 768 * K;
  const float* bd = bias + dir * 768;
  float* Cd = dir ? C1 : C0;
  const int tbase = dir ? tb1 : tb0;
  const int tid = threadIdx.x;
  const int tx = tid & 15, ty = tid >> 4;

  float acc[8][8];
  #pragma unroll
  for (int i = 0; i < 8; ++i)
    #pragma unroll
    for (int j = 0; j < 8; ++j) acc[i][j] = 0.f;

  const int KB = (K + 31) >> 5;
  for (int kb = 0; kb < KB; ++kb) {
    __syncthreads();
    #pragma unroll
    for (int e = 0; e < 16; ++e) {
      const int i = e * 256 + tid;
      const int r = i >> 5, kk = i & 31;
      const int kg = kb * 32 + kk;
      const int m = mt * 128 + r;
      long ar;
      if (CHUNKMAP) ar = (long)(m >> 7) * 512 + tbase + (m & 127);
      else          ar = m;
      As[kk][r] = (kg < K) ? A[ar * K + kg] : 0.f;
      Bs[kk][r] = (kg < K) ? Wd[(long)(nt * 128 + r) * K + kg] : 0.f;
    }
    __syncthreads();
    #pragma unroll 4
    for (int kk = 0; kk < 32; ++kk) {
      float a[8], b[8];
      #pragma unroll
      for (int i = 0; i < 8; ++i) a[i] = As[kk][i * 16 + ty];
      #pragma unroll
      for (int j = 0; j < 8; ++j) b[j] = Bs[kk][j * 16 + tx];
      #pragma unroll
      for (int i = 0; i < 8; ++i)
        #pragma unroll
        for (int j = 0; j < 8; ++j) acc[i][j] = fmaf(a[i], b[j], acc[i][j]);
    }
  }
  #pragma unroll
  for (int j = 0; j < 8; ++j) {
    const int n = nt * 128 + j * 16 + tx;
    const float bv = bd[n];
    #pragma unroll
    for (int i = 0; i < 8; ++i) {
      const int m = mt * 128 + i * 16 + ty;
      float v = acc[i][j] + bv;
      if (RELU) v = fmaxf(v, 0.f);
      Cd[(long)m * N + n] = v;
    }
  }
}

// Pin a float4 in VGPRs/AGPRs: opaque modification -> no rematerialization.
#define KEEP4(v) asm volatile("" : "+v"(v.x), "+v"(v.y), "+v"(v.z), "+v"(v.w))

// ---------------------------------------------------------------------------
// Persistent GRU recurrence, xg precomputed. 256 WGs x 768 threads.
// WG = (sgid = dir*32+group [2 batches], slice [64 hidden units]) -> 192 rows.
// Thread tile: 4 rows x 16 k x 2 batches (128 FMA), weights 16 float4 pinned.
//   rtile = tid>>4 (0..47): rows rtile*4..+4 ; kh = tid&15: k in [kh*16,+16).
// Reduction over the 16 k-slices via 4x shfl_xor butterfly (within wave).
// hcur padded: +4 floats per 16 (lane stride 80B -> 2-way bank alias, free).
// 4-wide same-XCD barrier per step; 128 steps per launch, state in stbuf.
// ---------------------------------------------------------------------------
template <int LAYER>
__global__ __launch_bounds__(768, 3) void rec_kernel(
    const float* __restrict__ xgf, const float* __restrict__ xgb,
    const float* __restrict__ whh, const float* __restrict__ bhh,
    const int* __restrict__ lens, float* __restrict__ out,
    float* __restrict__ stbuf, int* __restrict__ ctr_base, int sbase)
{
  __shared__ float hcur[2 * 336];   // [b][k + (k>>4)*4]
  __shared__ float ghs[2 * 200];    // [b][row], b-stride 200

  const int tid = threadIdx.x;
  const int bx = blockIdx.x;
  const int sgid = bx & 63, slice = bx >> 6;       // slice: 64 units
  const int dir = sgid >> 5, group = sgid & 31;    // group: 2 batches
  int* ctr = ctr_base + sgid * 16;

  const int lane = tid & 63;
  const int kh = tid & 15;          // k-slice
  const int rtile = tid >> 4;       // 0..47, rows rtile*4..+4

  // Weights: w[i*4+q] = Whh[dir][rg(i)][kh*16 + q*4 ..+4), 16 float4, pinned.
  float4 w[16];
  {
    #pragma unroll
    for (int i = 0; i < 4; ++i) {
      const int lr = rtile * 4 + i;
      const int gate = lr >> 6, ur = lr & 63;
      const int rg = gate * 256 + slice * 64 + ur;
      const float* wr = whh + ((long)dir * 768 + rg) * 256 + kh * 16;
      #pragma unroll
      for (int q = 0; q < 4; ++q) w[i * 4 + q] = ((const float4*)wr)[q];
    }
    #pragma unroll
    for (int iq = 0; iq < 16; ++iq) KEEP4(w[iq]);
  }

  // gate-thread setup (tid < 128): (bgate, u)
  const int bgate = tid >> 6, u = tid & 63;
  const int jg = slice * 64 + u;
  const int bg_g = group * 2 + bgate;
  float bhr = 0.f, bhz = 0.f, bhn = 0.f;
  int lenb = 1;
  if (tid < 128) {
    bhr = bhh[dir * 768 + jg];
    bhz = bhh[dir * 768 + 256 + jg];
    bhn = bhh[dir * 768 + 512 + jg];
    lenb = max(1, lens[bg_g]);
  }
  const float* xg_my = (dir == 0) ? xgf : xgb;

  if (sbase == 0) {  // chunk 0: zero state buf0, initial arrive
    if (tid < 128)
      stbuf[((dir * 2 + 0) * B_ + bg_g) * H_ + jg] = 0.f;
    __syncthreads();
    if (tid == 0)
      __hip_atomic_fetch_add(ctr, 1, __ATOMIC_RELEASE, __HIP_MEMORY_SCOPE_AGENT);
  }

  for (int ti = 0; ti < 128; ++ti) {
    const int s = sbase + ti;
    const int t = dir ? (T_ - 1 - s) : s;
    const int tt = dir ? (127 - ti) : ti;

    // xg prefetch (h-independent): issue BEFORE the barrier poll.
    float xrv = 0.f, xzv = 0.f, xnv = 0.f;
    if (tid < 128) {
      const float* xrow = xg_my + ((long)bg_g * 128 + tt) * 768;
      xrv = xrow[jg];
      xzv = xrow[256 + jg];
      xnv = xrow[512 + jg];
    }

    if (tid == 0) {
      const int tgt = 4 * (s + 1);
      while (__hip_atomic_load(ctr, __ATOMIC_RELAXED, __HIP_MEMORY_SCOPE_AGENT) < tgt) {}
      (void)__hip_atomic_load(ctr, __ATOMIC_ACQUIRE, __HIP_MEMORY_SCOPE_AGENT);
    }
    __syncthreads();  // S1: peers published step-s state

    // h staging: 2 batches x 256 floats (tid < 128, one float4 each, padded)
    if (tid < 128) {
      const int bl = tid >> 6, k4 = tid & 63;
      const int rb = s & 1;
      float4 v = *(const float4*)
          &stbuf[(((dir * 2 + rb) * B_) + group * 2 + bl) * H_ + k4 * 4];
      *(float4*)&hcur[bl * 336 + k4 * 4 + (k4 >> 2) * 4] = v;
    }
    __syncthreads();  // S2: h ready

    // E: 4 rows x 16 k x 2 batches; weights in registers, 8 h-b128 reads
    float a0[4], a1[4];
    {
      const float* hb0 = &hcur[kh * 20];
      const float* hb1 = &hcur[336 + kh * 20];
      float4 h0[4], h1v[4];
      #pragma unroll
      for (int q = 0; q < 4; ++q) h0[q]  = *(const float4*)&hb0[q * 4];
      #pragma unroll
      for (int q = 0; q < 4; ++q) h1v[q] = *(const float4*)&hb1[q * 4];
      #pragma unroll
      for (int i = 0; i < 4; ++i) { a0[i] = 0.f; a1[i] = 0.f; }
      #pragma unroll
      for (int q = 0; q < 4; ++q)
        #pragma unroll
        for (int i = 0; i < 4; ++i) {
          const float4 wv = w[i * 4 + q];
          a0[i] = fmaf(wv.x, h0[q].x, a0[i]);
          a0[i] = fmaf(wv.y, h0[q].y, a0[i]);
          a0[i] = fmaf(wv.z, h0[q].z, a0[i]);
          a0[i] = fmaf(wv.w, h0[q].w, a0[i]);
          a1[i] = fmaf(wv.x, h1v[q].x, a1[i]);
          a1[i] = fmaf(wv.y, h1v[q].y, a1[i]);
          a1[i] = fmaf(wv.z, h1v[q].z, a1[i]);
          a1[i] = fmaf(wv.w, h1v[q].w, a1[i]);
        }
      // butterfly over the 16 k-slices (lane bits 0..3)
      #pragma unroll
      for (int off = 1; off <= 8; off <<= 1) {
        #pragma unroll
        for (int i = 0; i < 4; ++i) {
          a0[i] += __shfl_xor(a0[i], off);
          a1[i] += __shfl_xor(a1[i], off);
        }
      }
      const int j = lane & 15;
      if (j < 8) {  // lane j writes acc[b=j>>2][i=j&3] (static-index selects)
        const int wb = j >> 2, wi = j & 3;
        float s0 = wb ? a1[0] : a0[0];
        float s1 = wb ? a1[1] : a0[1];
        float s2 = wb ? a1[2] : a0[2];
        float s3 = wb ? a1[3] : a0[3];
        float t0 = (wi & 1) ? s1 : s0;
        float t1 = (wi & 1) ? s3 : s2;
        float v  = (wi & 2) ? t1 : t0;
        ghs[wb * 200 + rtile * 4 + wi] = v;
      }
    }
    __syncthreads();  // S3: ghs ready

    // gates + publish
    if (tid < 128) {
      const float gr_ = ghs[bgate * 200 + u]       + bhr;
      const float gz_ = ghs[bgate * 200 + 64 + u]  + bhz;
      const float gn_ = ghs[bgate * 200 + 128 + u] + bhn;
      const float r_ = 1.f / (1.f + expf(-(xrv + gr_)));
      const float z_ = 1.f / (1.f + expf(-(xzv + gz_)));
      const float n_ = tanhf(xnv + r_ * gn_);
      const float hold = hcur[bgate * 336 + jg + (jg >> 4) * 4];
      const float hv = (t < lenb) ? ((1.f - z_) * n_ + z_ * hold) : hold;
      stbuf[((dir * 2 + ((s + 1) & 1)) * B_ + bg_g) * H_ + jg] = hv;
      if (LAYER == 0)
        out[((long)bg_g * T_ + t) * 512 + dir * 256 + jg] = hv;
      else if (s == T_ - 1)
        out[(dir * B_ + bg_g) * H_ + jg] = hv;
    }
    __syncthreads();  // S4: publishes drained before arrive
    if (tid == 0)
      __hip_atomic_fetch_add(ctr, 1, __ATOMIC_RELEASE, __HIP_MEMORY_SCOPE_AGENT);
  }
}

// ---------------------------------------------------------------------------
// Final: LayerNorm(concat(hf,hb)) @ fc_w^T + fc_b -> out[64][100]
// ---------------------------------------------------------------------------
__global__ __launch_bounds__(128) void final_kernel(
    const float* __restrict__ hfhb, const float* __restrict__ lng,
    const float* __restrict__ lnb, const float* __restrict__ fcw,
    const float* __restrict__ fcb, float* __restrict__ out)
{
  const int b = blockIdx.x, tid = threadIdx.x;
  __shared__ float y[512];
  __shared__ float wsum[2], wsum2[2];
  float s = 0.f, s2 = 0.f;
  for (int i = tid; i < 512; i += 128) {
    float v = (i < 256) ? hfhb[b * 256 + i] : hfhb[(64 + b) * 256 + (i - 256)];
    y[i] = v; s += v; s2 += v * v;
  }
  for (int off = 32; off; off >>= 1) { s += __shfl_down(s, off); s2 += __shfl_down(s2, off); }
  const int wv = tid >> 6;
  if ((tid & 63) == 0) { wsum[wv] = s; wsum2[wv] = s2; }
  __syncthreads();
  const float S = wsum[0] + wsum[1], S2 = wsum2[0] + wsum2[1];
  const float mu = S / 512.f;
  const float var = S2 / 512.f - mu * mu;
  const float rs = rsqrtf(var + 1e-5f);
  for (int i = tid; i < 512; i += 128) y[i] = (y[i] - mu) * rs * lng[i] + lnb[i];
  __syncthreads();
  for (int c = tid; c < 100; c += 128) {
    float acc = fcb[c];
    const float* wr = &fcw[c * 512];
    #pragma unroll 4
    for (int k = 0; k < 512; ++k) acc = fmaf(y[k], wr[k], acc);
    out[b * 100 + c] = acc;
  }
}

// ---------------------------------------------------------------------------
extern "C" void kernel_launch(void* const* d_in, const int* in_sizes, int n_in,
                              void* d_out, int out_size, void* d_ws, size_t ws_size,
                              hipStream_t stream)
{
  (void)in_sizes; (void)n_in; (void)out_size; (void)ws_size;
  const float* x    = (const float*)d_in[0];
  const float* pw   = (const float*)d_in[1];
  const float* pb   = (const float*)d_in[2];
  const float* wih0 = (const float*)d_in[3];
  const float* whh0 = (const float*)d_in[4];
  const float* bih0 = (const float*)d_in[5];
  const float* bhh0 = (const float*)d_in[6];
  const float* wih1 = (const float*)d_in[7];
  const float* whh1 = (const float*)d_in[8];
  const float* bih1 = (const float*)d_in[9];
  const float* bhh1 = (const float*)d_in[10];
  const float* lng  = (const float*)d_in[11];
  const float* lnb  = (const float*)d_in[12];
  const float* fcw  = (const float*)d_in[13];
  const float* fcb  = (const float*)d_in[14];
  const int*   lens = (const int*)d_in[15];
  float* out = (float*)d_out;

  char* ws = (char*)d_ws;
  int*   ctr   = (int*)ws;                       // 16 KB: L0 at +0, L1 at +1024 ints
  float* hproj = (float*)(ws + 16384);           // 32768x128   (16.78 MB)
  float* h1    = (float*)(ws + 16793600);        // 32768x512   (67.11 MB)
  float* xgf   = (float*)(ws + 83902464);        // 64x128x768  (25.17 MB)
  float* xgb   = (float*)(ws + 109068288);       // 64x128x768  (25.17 MB)
  float* stbuf = (float*)(ws + 134234112);       // 2x2x64x256  (0.52 MB)
  float* hfhb  = (float*)(ws + 134758400);       // 2x64x256    (0.13 MB)

  hipMemsetAsync(ctr, 0, 16384, stream);

  // proj: relu(x @ pw^T + pb) -> hproj  (M=32768, N=128, K=258)
  gemm_kernel<false, true><<<dim3(256), dim3(256), 0, stream>>>(
      x, pw, pb, hproj, hproj, 258, 128, 256, 1, 0, 0);

  // Layer 0: per phase p, xg for fwd chunk p and bwd chunk 3-p, then 128 rec steps
  for (int p = 0; p < 4; ++p) {
    gemm_kernel<true, false><<<dim3(768), dim3(256), 0, stream>>>(
        hproj, wih0, bih0, xgf, xgb, 128, 768, 64, 6, p * 128, (3 - p) * 128);
    rec_kernel<0><<<dim3(256), dim3(768), 0, stream>>>(
        xgf, xgb, whh0, bhh0, lens, h1, stbuf, ctr, p * 128);
  }
  // Layer 1
  for (int p = 0; p < 4; ++p) {
    gemm_kernel<true, false><<<dim3(768), dim3(256), 0, stream>>>(
        h1, wih1, bih1, xgf, xgb, 512, 768, 64, 6, p * 128, (3 - p) * 128);
    rec_kernel<1><<<dim3(256), dim3(768), 0, stream>>>(
        xgf, xgb, whh1, bhh1, lens, hfhb, stbuf, ctr + 1024, p * 128);
  }

  final_kernel<<<dim3(64), dim3(128), 0, stream>>>(hfhb, lng, lnb, fcw, fcb, out);
}

// Round 7
// 5091.760 us; speedup vs baseline: 2.3123x; 1.5210x over previous
//
#include <hip/hip_runtime.h>
#include <math.h>

constexpr int B_ = 64, T_ = 512, H_ = 256;

// ---------------------------------------------------------------------------
// Generic tiled fp32 GEMM: C[m][n] = act( sum_k A[arow(m)][k]*W[n][k] + bias[n] )
// BM=BN=128, BK=32, 256 threads, 8x8 micro-tile. grid = mtiles*ntiles*dirs.
// CHUNKMAP: A row = (m>>7)*512 + tbase + (m&127)  (b-major chunks of 128 t)
// ---------------------------------------------------------------------------
template <bool CHUNKMAP, bool RELU>
__global__ __launch_bounds__(256) void gemm_kernel(
    const float* __restrict__ A, const float* __restrict__ Wt,
    const float* __restrict__ bias, float* __restrict__ C0,
    float* __restrict__ C1, int K, int N, int mtiles, int ntiles,
    int tb0, int tb1)
{
  __shared__ float As[32][132];
  __shared__ float Bs[32][132];
  int bxx = blockIdx.x;
  const int mt = bxx % mtiles; bxx /= mtiles;
  const int nt = bxx % ntiles; const int dir = bxx / ntiles;
  const float* Wd = Wt + (long)dir * 768 * K;
  const float* bd = bias + dir * 768;
  float* Cd = dir ? C1 : C0;
  const int tbase = dir ? tb1 : tb0;
  const int tid = threadIdx.x;
  const int tx = tid & 15, ty = tid >> 4;

  float acc[8][8];
  #pragma unroll
  for (int i = 0; i < 8; ++i)
    #pragma unroll
    for (int j = 0; j < 8; ++j) acc[i][j] = 0.f;

  const int KB = (K + 31) >> 5;
  for (int kb = 0; kb < KB; ++kb) {
    __syncthreads();
    #pragma unroll
    for (int e = 0; e < 16; ++e) {
      const int i = e * 256 + tid;
      const int r = i >> 5, kk = i & 31;
      const int kg = kb * 32 + kk;
      const int m = mt * 128 + r;
      long ar;
      if (CHUNKMAP) ar = (long)(m >> 7) * 512 + tbase + (m & 127);
      else          ar = m;
      As[kk][r] = (kg < K) ? A[ar * K + kg] : 0.f;
      Bs[kk][r] = (kg < K) ? Wd[(long)(nt * 128 + r) * K + kg] : 0.f;
    }
    __syncthreads();
    #pragma unroll 4
    for (int kk = 0; kk < 32; ++kk) {
      float a[8], b[8];
      #pragma unroll
      for (int i = 0; i < 8; ++i) a[i] = As[kk][i * 16 + ty];
      #pragma unroll
      for (int j = 0; j < 8; ++j) b[j] = Bs[kk][j * 16 + tx];
      #pragma unroll
      for (int i = 0; i < 8; ++i)
        #pragma unroll
        for (int j = 0; j < 8; ++j) acc[i][j] = fmaf(a[i], b[j], acc[i][j]);
    }
  }
  #pragma unroll
  for (int j = 0; j < 8; ++j) {
    const int n = nt * 128 + j * 16 + tx;
    const float bv = bd[n];
    #pragma unroll
    for (int i = 0; i < 8; ++i) {
      const int m = mt * 128 + i * 16 + ty;
      float v = acc[i][j] + bv;
      if (RELU) v = fmaxf(v, 0.f);
      Cd[(long)m * N + n] = v;
    }
  }
}

// Pin a float4 in VGPRs/AGPRs: opaque modification -> no rematerialization.
#define KEEP4(v) asm volatile("" : "+v"(v.x), "+v"(v.y), "+v"(v.z), "+v"(v.w))

// --- system-scope (L3 coherence point) memory helpers: bypass per-XCD L2 ---
__device__ __forceinline__ void st_sys_f1(float* p, float v) {
  asm volatile("global_store_dword %0, %1, off sc0 sc1"
               :: "v"(p), "v"(v) : "memory");
}
__device__ __forceinline__ float4 ld_sys_f4(const float* p) {
  float4 d;
  asm volatile("global_load_dwordx4 %0, %1, off sc0 sc1"
               : "=v"(d) : "v"(p) : "memory");
  asm volatile("s_waitcnt vmcnt(0)" ::: "memory");
  return d;
}
__device__ __forceinline__ int ld_sys_i1(const int* p) {
  int d;
  asm volatile("global_load_dword %0, %1, off sc0 sc1"
               : "=v"(d) : "v"(p) : "memory");
  asm volatile("s_waitcnt vmcnt(0)" ::: "memory");
  return d;
}
__device__ __forceinline__ void wait_vm0() {
  asm volatile("s_waitcnt vmcnt(0)" ::: "memory");
}

// ---------------------------------------------------------------------------
// Persistent GRU recurrence, xg precomputed. 256 WGs x 768 threads.
// WG = (sgid = dir*32+group [2 batches], slice [64 hidden units]) -> 192 rows.
// Thread tile: 4 rows x 16 k x 2 batches (128 FMA), weights 16 float4 pinned.
// Cross-WG h exchange entirely through the L3 coherence point (sc0 sc1 ops):
// publish h (sc1 stores) -> per-wave vmcnt(0) -> syncthreads -> RELAXED atomic;
// reader polls ctr (sc1 load) then stages h (sc1 loads). No release/acquire
// fences -> no buffer_wbl2/buffer_inv L2 maintenance per step (r6's stall).
// ---------------------------------------------------------------------------
template <int LAYER>
__global__ __launch_bounds__(768, 3) void rec_kernel(
    const float* __restrict__ xgf, const float* __restrict__ xgb,
    const float* __restrict__ whh, const float* __restrict__ bhh,
    const int* __restrict__ lens, float* __restrict__ out,
    float* __restrict__ stbuf, int* __restrict__ ctr_base, int sbase)
{
  __shared__ float hcur[2 * 336];   // [b][k + (k>>4)*4]
  __shared__ float ghs[2 * 200];    // [b][row], b-stride 200

  const int tid = threadIdx.x;
  const int bx = blockIdx.x;
  const int sgid = bx & 63, slice = bx >> 6;       // slice: 64 units
  const int dir = sgid >> 5, group = sgid & 31;    // group: 2 batches
  int* ctr = ctr_base + sgid * 16;

  const int lane = tid & 63;
  const int kh = tid & 15;          // k-slice
  const int rtile = tid >> 4;       // 0..47, rows rtile*4..+4

  // Weights: w[i*4+q] = Whh[dir][rg(i)][kh*16 + q*4 ..+4), 16 float4, pinned.
  float4 w[16];
  {
    #pragma unroll
    for (int i = 0; i < 4; ++i) {
      const int lr = rtile * 4 + i;
      const int gate = lr >> 6, ur = lr & 63;
      const int rg = gate * 256 + slice * 64 + ur;
      const float* wr = whh + ((long)dir * 768 + rg) * 256 + kh * 16;
      #pragma unroll
      for (int q = 0; q < 4; ++q) w[i * 4 + q] = ((const float4*)wr)[q];
    }
    #pragma unroll
    for (int iq = 0; iq < 16; ++iq) KEEP4(w[iq]);
  }

  // gate-thread setup (tid < 128): (bgate, u)
  const int bgate = tid >> 6, u = tid & 63;
  const int jg = slice * 64 + u;
  const int bg_g = group * 2 + bgate;
  float bhr = 0.f, bhz = 0.f, bhn = 0.f;
  int lenb = 1;
  if (tid < 128) {
    bhr = bhh[dir * 768 + jg];
    bhz = bhh[dir * 768 + 256 + jg];
    bhn = bhh[dir * 768 + 512 + jg];
    lenb = max(1, lens[bg_g]);
  }
  const float* xg_my = (dir == 0) ? xgf : xgb;

  if (sbase == 0) {  // chunk 0: zero state buf0 (sc1), initial arrive
    if (tid < 128)
      st_sys_f1(&stbuf[((dir * 2 + 0) * B_ + bg_g) * H_ + jg], 0.f);
    wait_vm0();
    __syncthreads();
    if (tid == 0)
      __hip_atomic_fetch_add(ctr, 1, __ATOMIC_RELAXED, __HIP_MEMORY_SCOPE_AGENT);
  }

  for (int ti = 0; ti < 128; ++ti) {
    const int s = sbase + ti;
    const int t = dir ? (T_ - 1 - s) : s;
    const int tt = dir ? (127 - ti) : ti;

    // xg prefetch (h-independent): issue BEFORE the barrier poll.
    float xrv = 0.f, xzv = 0.f, xnv = 0.f;
    if (tid < 128) {
      const float* xrow = xg_my + ((long)bg_g * 128 + tt) * 768;
      xrv = xrow[jg];
      xzv = xrow[256 + jg];
      xnv = xrow[512 + jg];
    }

    if (tid == 0) {
      const int tgt = 4 * (s + 1);
      while (ld_sys_i1(ctr) < tgt) {}
    }
    __syncthreads();  // S1: peers published step-s state (visible at L3)

    // h staging: 2 batches x 256 floats (tid < 128, one sc1 float4 each)
    if (tid < 128) {
      const int bl = tid >> 6, k4 = tid & 63;
      const int rb = s & 1;
      float4 v = ld_sys_f4(
          &stbuf[(((dir * 2 + rb) * B_) + group * 2 + bl) * H_ + k4 * 4]);
      *(float4*)&hcur[bl * 336 + k4 * 4 + (k4 >> 2) * 4] = v;
    }
    __syncthreads();  // S2: h ready

    // E: 4 rows x 16 k x 2 batches; weights in registers, 8 h-b128 reads
    float a0[4], a1[4];
    {
      const float* hb0 = &hcur[kh * 20];
      const float* hb1 = &hcur[336 + kh * 20];
      float4 h0[4], h1v[4];
      #pragma unroll
      for (int q = 0; q < 4; ++q) h0[q]  = *(const float4*)&hb0[q * 4];
      #pragma unroll
      for (int q = 0; q < 4; ++q) h1v[q] = *(const float4*)&hb1[q * 4];
      #pragma unroll
      for (int i = 0; i < 4; ++i) { a0[i] = 0.f; a1[i] = 0.f; }
      #pragma unroll
      for (int q = 0; q < 4; ++q)
        #pragma unroll
        for (int i = 0; i < 4; ++i) {
          const float4 wv = w[i * 4 + q];
          a0[i] = fmaf(wv.x, h0[q].x, a0[i]);
          a0[i] = fmaf(wv.y, h0[q].y, a0[i]);
          a0[i] = fmaf(wv.z, h0[q].z, a0[i]);
          a0[i] = fmaf(wv.w, h0[q].w, a0[i]);
          a1[i] = fmaf(wv.x, h1v[q].x, a1[i]);
          a1[i] = fmaf(wv.y, h1v[q].y, a1[i]);
          a1[i] = fmaf(wv.z, h1v[q].z, a1[i]);
          a1[i] = fmaf(wv.w, h1v[q].w, a1[i]);
        }
      // butterfly over the 16 k-slices (lane bits 0..3)
      #pragma unroll
      for (int off = 1; off <= 8; off <<= 1) {
        #pragma unroll
        for (int i = 0; i < 4; ++i) {
          a0[i] += __shfl_xor(a0[i], off);
          a1[i] += __shfl_xor(a1[i], off);
        }
      }
      const int j = lane & 15;
      if (j < 8) {  // lane j writes acc[b=j>>2][i=j&3] (static-index selects)
        const int wb = j >> 2, wi = j & 3;
        float s0 = wb ? a1[0] : a0[0];
        float s1 = wb ? a1[1] : a0[1];
        float s2 = wb ? a1[2] : a0[2];
        float s3 = wb ? a1[3] : a0[3];
        float t0 = (wi & 1) ? s1 : s0;
        float t1 = (wi & 1) ? s3 : s2;
        float v  = (wi & 2) ? t1 : t0;
        ghs[wb * 200 + rtile * 4 + wi] = v;
      }
    }
    __syncthreads();  // S3: ghs ready

    // gates + publish (h state via sc1 stores; out via normal cached stores)
    if (tid < 128) {
      const float gr_ = ghs[bgate * 200 + u]       + bhr;
      const float gz_ = ghs[bgate * 200 + 64 + u]  + bhz;
      const float gn_ = ghs[bgate * 200 + 128 + u] + bhn;
      const float r_ = 1.f / (1.f + expf(-(xrv + gr_)));
      const float z_ = 1.f / (1.f + expf(-(xzv + gz_)));
      const float n_ = tanhf(xnv + r_ * gn_);
      const float hold = hcur[bgate * 336 + jg + (jg >> 4) * 4];
      const float hv = (t < lenb) ? ((1.f - z_) * n_ + z_ * hold) : hold;
      st_sys_f1(&stbuf[((dir * 2 + ((s + 1) & 1)) * B_ + bg_g) * H_ + jg], hv);
      if (LAYER == 0)
        out[((long)bg_g * T_ + t) * 512 + dir * 256 + jg] = hv;
      else if (s == T_ - 1)
        out[(dir * B_ + bg_g) * H_ + jg] = hv;
    }
    wait_vm0();       // each wave drains its own sc1 stores
    __syncthreads();  // S4: all publishes at L3 before arrive
    if (tid == 0)
      __hip_atomic_fetch_add(ctr, 1, __ATOMIC_RELAXED, __HIP_MEMORY_SCOPE_AGENT);
  }
}

// ---------------------------------------------------------------------------
// Final: LayerNorm(concat(hf,hb)) @ fc_w^T + fc_b -> out[64][100]
// ---------------------------------------------------------------------------
__global__ __launch_bounds__(128) void final_kernel(
    const float* __restrict__ hfhb, const float* __restrict__ lng,
    const float* __restrict__ lnb, const float* __restrict__ fcw,
    const float* __restrict__ fcb, float* __restrict__ out)
{
  const int b = blockIdx.x, tid = threadIdx.x;
  __shared__ float y[512];
  __shared__ float wsum[2], wsum2[2];
  float s = 0.f, s2 = 0.f;
  for (int i = tid; i < 512; i += 128) {
    float v = (i < 256) ? hfhb[b * 256 + i] : hfhb[(64 + b) * 256 + (i - 256)];
    y[i] = v; s += v; s2 += v * v;
  }
  for (int off = 32; off; off >>= 1) { s += __shfl_down(s, off); s2 += __shfl_down(s2, off); }
  const int wv = tid >> 6;
  if ((tid & 63) == 0) { wsum[wv] = s; wsum2[wv] = s2; }
  __syncthreads();
  const float S = wsum[0] + wsum[1], S2 = wsum2[0] + wsum2[1];
  const float mu = S / 512.f;
  const float var = S2 / 512.f - mu * mu;
  const float rs = rsqrtf(var + 1e-5f);
  for (int i = tid; i < 512; i += 128) y[i] = (y[i] - mu) * rs * lng[i] + lnb[i];
  __syncthreads();
  for (int c = tid; c < 100; c += 128) {
    float acc = fcb[c];
    const float* wr = &fcw[c * 512];
    #pragma unroll 4
    for (int k = 0; k < 512; ++k) acc = fmaf(y[k], wr[k], acc);
    out[b * 100 + c] = acc;
  }
}

// ---------------------------------------------------------------------------
extern "C" void kernel_launch(void* const* d_in, const int* in_sizes, int n_in,
                              void* d_out, int out_size, void* d_ws, size_t ws_size,
                              hipStream_t stream)
{
  (void)in_sizes; (void)n_in; (void)out_size; (void)ws_size;
  const float* x    = (const float*)d_in[0];
  const float* pw   = (const float*)d_in[1];
  const float* pb   = (const float*)d_in[2];
  const float* wih0 = (const float*)d_in[3];
  const float* whh0 = (const float*)d_in[4];
  const float* bih0 = (const float*)d_in[5];
  const float* bhh0 = (const float*)d_in[6];
  const float* wih1 = (const float*)d_in[7];
  const float* whh1 = (const float*)d_in[8];
  const float* bih1 = (const float*)d_in[9];
  const float* bhh1 = (const float*)d_in[10];
  const float* lng  = (const float*)d_in[11];
  const float* lnb  = (const float*)d_in[12];
  const float* fcw  = (const float*)d_in[13];
  const float* fcb  = (const float*)d_in[14];
  const int*   lens = (const int*)d_in[15];
  float* out = (float*)d_out;

  char* ws = (char*)d_ws;
  int*   ctr   = (int*)ws;                       // 16 KB: L0 at +0, L1 at +1024 ints
  float* hproj = (float*)(ws + 16384);           // 32768x128   (16.78 MB)
  float* h1    = (float*)(ws + 16793600);        // 32768x512   (67.11 MB)
  float* xgf   = (float*)(ws + 83902464);        // 64x128x768  (25.17 MB)
  float* xgb   = (float*)(ws + 109068288);       // 64x128x768  (25.17 MB)
  float* stbuf = (float*)(ws + 134234112);       // 2x2x64x256  (0.52 MB)
  float* hfhb  = (float*)(ws + 134758400);       // 2x64x256    (0.13 MB)

  hipMemsetAsync(ctr, 0, 16384, stream);

  // proj: relu(x @ pw^T + pb) -> hproj  (M=32768, N=128, K=258)
  gemm_kernel<false, true><<<dim3(256), dim3(256), 0, stream>>>(
      x, pw, pb, hproj, hproj, 258, 128, 256, 1, 0, 0);

  // Layer 0: per phase p, xg for fwd chunk p and bwd chunk 3-p, then 128 rec steps
  for (int p = 0; p < 4; ++p) {
    gemm_kernel<true, false><<<dim3(768), dim3(256), 0, stream>>>(
        hproj, wih0, bih0, xgf, xgb, 128, 768, 64, 6, p * 128, (3 - p) * 128);
    rec_kernel<0><<<dim3(256), dim3(768), 0, stream>>>(
        xgf, xgb, whh0, bhh0, lens, h1, stbuf, ctr, p * 128);
  }
  // Layer 1
  for (int p = 0; p < 4; ++p) {
    gemm_kernel<true, false><<<dim3(768), dim3(256), 0, stream>>>(
        h1, wih1, bih1, xgf, xgb, 512, 768, 64, 6, p * 128, (3 - p) * 128);
    rec_kernel<1><<<dim3(256), dim3(768), 0, stream>>>(
        xgf, xgb, whh1, bhh1, lens, hfhb, stbuf, ctr + 1024, p * 128);
  }

  final_kernel<<<dim3(64), dim3(128), 0, stream>>>(hfhb, lng, lnb, fcw, fcb, out);
}